// Round 9
// baseline (106.584 us; speedup 1.0000x reference)
//
#include <hip/hip_runtime.h>

typedef unsigned int u32;
typedef unsigned short u16;
typedef __attribute__((ext_vector_type(8))) short bf16x8;   // 8 bf16 in 4 VGPRs
typedef __attribute__((ext_vector_type(4))) float f32x4;

#define NPIX 110592            // 48^3
#define NTILES 1728            // NPIX/64 per batch
#define K1_BLOCKS 864          // each block: 4 tiles, b-aligned
#define K1_TPB 4
#define PART_STRIDE 4224       // 4096 ctx + 128 rowsum

// ws layout (4-byte slots)
#define WS_CTX   0             // 2*4096 f32
#define WS_RS    8192          // 2*128 f32
#define WS_ATB   8448          // 2*4096 u32 (packed bf16 pairs of A^T)
#define WS_PART  16640

union FragU { u32 u[4]; bf16x8 v; };

#define MFMA(a,b,c) __builtin_amdgcn_mfma_f32_16x16x32_bf16((a),(b),(c),0,0,0)

__device__ __forceinline__ void gll16(const float* g, float* l) {
    typedef const __attribute__((address_space(1))) unsigned int* gp_t;
    typedef __attribute__((address_space(3))) unsigned int* lp_t;
    __builtin_amdgcn_global_load_lds((gp_t)g, (lp_t)l, 16, 0, 0);
}
__device__ __forceinline__ u32 f2bf(float f) {            // RNE f32->bf16 bits
    u32 u = __float_as_uint(f);
    return (u + 0x7FFFu + ((u >> 16) & 1u)) >> 16;
}
__device__ __forceinline__ float bf2f(u32 bits) { return __uint_as_float(bits << 16); }
__device__ __forceinline__ u32 pk2(float a, float b) { return f2bf(a) | (f2bf(b) << 16); }
__device__ __forceinline__ void split2(float a, float b, u32& hi, u32& lo) {
    u32 ha = f2bf(a), hb = f2bf(b);
    hi = ha | (hb << 16);
    lo = pk2(a - bf2f(ha), b - bf2f(hb));
}

// ---------------- K1: k,v GEMM (MFMA) + ctx/rowsum (MFMA) ----------------
// R8 structure; ONE change: phase-1 operand swap MFMA(x,W) -> D[px][o], so
// each lane's 4 acc = 4 consecutive px at one o -> b64 kvb stores (16 vs 64
// scattered u16). Fragments & phase-2 reads unchanged (A/B lane layouts
// are identical in MFMA; products commuted => identical numerics).
__global__ __launch_bounds__(256, 2)
void k1_ctx(const float* __restrict__ x, const float* __restrict__ wq,
            float* __restrict__ part, int usePart, int R) {
    __shared__ float xt[64 * 64];      // [c][px] f32, 16 KB
    __shared__ u32   xbh[64 * 32];     // [px][cpair hi], swizzled, 8 KB
    __shared__ u32   xbl[64 * 32];     // [px][cpair lo], 8 KB
    __shared__ u32   kvb[256 * 32];    // [row][px-pair] bf16, swizzled, 32 KB
    const int blk = blockIdx.x;
    const int p   = threadIdx.x & 63;
    const int og  = __builtin_amdgcn_readfirstlane(threadIdx.x >> 6);
    const int b   = blk / (K1_BLOCKS / 2);
    const int q   = p >> 4;
    const int l15 = p & 15;
    const int yv  = (p & 7) << 2;
    const float* xg = x + (long)b * 64 * NPIX;
    const int srow = p >> 4, scol = (p & 15) << 2;

    // W fragments (rows 128+og*64..+64), split hi/lo, resident in VGPRs
    FragU wh[4][2], wl[4][2];
    #pragma unroll
    for (int mi = 0; mi < 4; ++mi)
        #pragma unroll
        for (int ks = 0; ks < 2; ++ks) {
            const int row = 128 + og * 64 + mi * 16 + l15;
            const float* wp = wq + row * 64 + ks * 32 + q * 4;
            float4 f0 = *(const float4*)wp;
            float4 f1 = *(const float4*)(wp + 16);
            split2(f0.x, f0.y, wh[mi][ks].u[0], wl[mi][ks].u[0]);
            split2(f0.z, f0.w, wh[mi][ks].u[1], wl[mi][ks].u[1]);
            split2(f1.x, f1.y, wh[mi][ks].u[2], wl[mi][ks].u[2]);
            split2(f1.z, f1.w, wh[mi][ks].u[3], wl[mi][ks].u[3]);
        }

    FragU ones;
    #pragma unroll
    for (int i = 0; i < 4; ++i) ones.u[i] = 0x3F803F80u;

    f32x4 cc[2][2], rsa[2];
    #pragma unroll
    for (int mi = 0; mi < 2; ++mi) {
        #pragma unroll
        for (int ni = 0; ni < 2; ++ni) cc[mi][ni] = (f32x4)0.f;
        rsa[mi] = (f32x4)0.f;
    }

    {   // prologue: stage tile 0
        const long i0 = (long)(blk * K1_TPB - b * NTILES) * 64;
        #pragma unroll
        for (int i = 0; i < 4; ++i) {
            const int r0 = og * 16 + i * 4;
            gll16(xg + (long)(r0 + srow) * NPIX + i0 + scol, &xt[r0 * 64]);
        }
    }

    #pragma unroll 1
    for (int tt = 0; tt < K1_TPB; ++tt) {
        asm volatile("s_waitcnt vmcnt(0)" ::: "memory");
        __syncthreads();                         // xt staged; prev phase2 done

        // transpose-pack xt -> split bf16 xbh/xbl
        {
            const int px = threadIdx.x & 63;
            const int cg = threadIdx.x >> 6;     // 0..3
            u32 hb_[8], lb_[8];
            #pragma unroll
            for (int w = 0; w < 8; ++w) {
                const int c = (cg * 8 + w) * 2;
                split2(xt[c * 64 + px], xt[(c + 1) * 64 + px], hb_[w], lb_[w]);
            }
            const int yy = (px & 7) << 2;
            const int sA = (cg * 8) ^ yy;
            const int sB = (cg * 8 + 4) ^ yy;
            *(uint4*)&xbh[px * 32 + sA] = make_uint4(hb_[0], hb_[1], hb_[2], hb_[3]);
            *(uint4*)&xbh[px * 32 + sB] = make_uint4(hb_[4], hb_[5], hb_[6], hb_[7]);
            *(uint4*)&xbl[px * 32 + sA] = make_uint4(lb_[0], lb_[1], lb_[2], lb_[3]);
            *(uint4*)&xbl[px * 32 + sB] = make_uint4(lb_[4], lb_[5], lb_[6], lb_[7]);
        }
        __syncthreads();                         // xb ready, xt consumed

        if (tt + 1 < K1_TPB) {                   // prefetch next tile's x
            const long i0 = (long)(blk * K1_TPB + tt + 1 - b * NTILES) * 64;
            #pragma unroll
            for (int i = 0; i < 4; ++i) {
                const int r0 = og * 16 + i * 4;
                gll16(xg + (long)(r0 + srow) * NPIX + i0 + scol, &xt[r0 * 64]);
            }
        }

        // phase 1: D[px][o] = (x^T W^T) via MFMA(x_frag, w_frag) — operands
        // swapped vs R8; fragments identical, products commuted.
        f32x4 a1[4][4];
        #pragma unroll
        for (int mi = 0; mi < 4; ++mi)
            #pragma unroll
            for (int ni = 0; ni < 4; ++ni) a1[mi][ni] = (f32x4)0.f;
        #pragma unroll
        for (int ni = 0; ni < 4; ++ni) {
            const int rb = (ni * 16 + l15) * 32;
            FragU bh[2], bl[2];
            #pragma unroll
            for (int ks = 0; ks < 2; ++ks) {
                const int c0 = (ks * 16 + 2 * q) ^ yv;
                const int c1 = (ks * 16 + 2 * q + 8) ^ yv;
                uint2 t0 = *(const uint2*)&xbh[rb + c0];
                uint2 t1 = *(const uint2*)&xbh[rb + c1];
                bh[ks].u[0] = t0.x; bh[ks].u[1] = t0.y;
                bh[ks].u[2] = t1.x; bh[ks].u[3] = t1.y;
                uint2 s0 = *(const uint2*)&xbl[rb + c0];
                uint2 s1 = *(const uint2*)&xbl[rb + c1];
                bl[ks].u[0] = s0.x; bl[ks].u[1] = s0.y;
                bl[ks].u[2] = s1.x; bl[ks].u[3] = s1.y;
            }
            #pragma unroll
            for (int mi = 0; mi < 4; ++mi)
                #pragma unroll
                for (int ks = 0; ks < 2; ++ks) {
                    a1[mi][ni] = MFMA(bh[ks].v, wh[mi][ks].v, a1[mi][ni]);
                    a1[mi][ni] = MFMA(bl[ks].v, wh[mi][ks].v, a1[mi][ni]);
                    a1[mi][ni] = MFMA(bh[ks].v, wl[mi][ks].v, a1[mi][ni]);
                }
        }

        // epilogue: exp on K-waves, pack px-pairs, b64 stores into kvb
        const bool isK = og < 2;
        #pragma unroll
        for (int mi = 0; mi < 4; ++mi) {
            const int row = og * 64 + mi * 16 + l15;   // o row of kvb
            const int X   = ((row >> 2) & 7) << 2;     // same swizzle as reads
            #pragma unroll
            for (int ni = 0; ni < 4; ++ni) {
                float v0 = a1[mi][ni][0], v1 = a1[mi][ni][1];
                float v2 = a1[mi][ni][2], v3 = a1[mi][ni][3];
                if (isK) {
                    v0 = __expf(v0); v1 = __expf(v1);
                    v2 = __expf(v2); v3 = __expf(v3);
                }
                const int pair0 = ni * 8 + q * 2;      // px-pair index (even)
                *(uint2*)&kvb[row * 32 + (pair0 ^ X)] =
                    make_uint2(pk2(v0, v1), pk2(v2, v3));
            }
        }
        __syncthreads();                         // kvb ready

        // phase 2: ctx(32x32) += EK x V^T, rowsum via B=ones — unchanged
        const int hb0 = og * 32;
        const int hb1 = 128 + og * 32;
        #pragma unroll
        for (int ksp = 0; ksp < 2; ++ksp) {
            FragU ak[2], av[2];
            #pragma unroll
            for (int mi = 0; mi < 2; ++mi) {
                {
                    const int row = hb0 + mi * 16 + l15;
                    const int Xr = ((row >> 2) & 7) << 2;
                    const int p0 = (ksp * 16 + 2 * q) ^ Xr;
                    const int p1 = (ksp * 16 + 2 * q + 8) ^ Xr;
                    uint2 t0 = *(const uint2*)&kvb[row * 32 + p0];
                    uint2 t1 = *(const uint2*)&kvb[row * 32 + p1];
                    ak[mi].u[0] = t0.x; ak[mi].u[1] = t0.y;
                    ak[mi].u[2] = t1.x; ak[mi].u[3] = t1.y;
                }
                {
                    const int row = hb1 + mi * 16 + l15;
                    const int Xr = ((row >> 2) & 7) << 2;
                    const int p0 = (ksp * 16 + 2 * q) ^ Xr;
                    const int p1 = (ksp * 16 + 2 * q + 8) ^ Xr;
                    uint2 t0 = *(const uint2*)&kvb[row * 32 + p0];
                    uint2 t1 = *(const uint2*)&kvb[row * 32 + p1];
                    av[mi].u[0] = t0.x; av[mi].u[1] = t0.y;
                    av[mi].u[2] = t1.x; av[mi].u[3] = t1.y;
                }
            }
            #pragma unroll
            for (int mi = 0; mi < 2; ++mi) {
                #pragma unroll
                for (int ni = 0; ni < 2; ++ni)
                    cc[mi][ni] = MFMA(ak[mi].v, av[ni].v, cc[mi][ni]);
                rsa[mi] = MFMA(ak[mi].v, ones.v, rsa[mi]);
            }
        }
    }

    // epilogue: per-block partials (or atomic replicas) — unchanged
    if (usePart) {
        float* pp = part + (long)blk * PART_STRIDE;
        #pragma unroll
        for (int mi = 0; mi < 2; ++mi)
            #pragma unroll
            for (int ni = 0; ni < 2; ++ni)
                #pragma unroll
                for (int j = 0; j < 4; ++j)
                    pp[og * 1024 + (mi * 16 + q * 4 + j) * 32 + ni * 16 + l15] = cc[mi][ni][j];
        if (l15 == 0) {
            #pragma unroll
            for (int mi = 0; mi < 2; ++mi)
                #pragma unroll
                for (int j = 0; j < 4; ++j)
                    pp[4096 + og * 32 + mi * 16 + q * 4 + j] = rsa[mi][j];
        }
    } else {
        float* pp = part + (long)(b * R + (blk % R)) * PART_STRIDE;
        #pragma unroll
        for (int mi = 0; mi < 2; ++mi)
            #pragma unroll
            for (int ni = 0; ni < 2; ++ni)
                #pragma unroll
                for (int j = 0; j < 4; ++j)
                    atomicAdd(&pp[og * 1024 + (mi * 16 + q * 4 + j) * 32 + ni * 16 + l15], cc[mi][ni][j]);
        if (l15 == 0) {
            #pragma unroll
            for (int mi = 0; mi < 2; ++mi)
                #pragma unroll
                for (int j = 0; j < 4; ++j)
                    atomicAdd(&pp[4096 + og * 32 + mi * 16 + q * 4 + j], rsa[mi][j]);
        }
    }
}

// ---------------- K1b: reduce partials -> ctx, rsum (atomic, sliced) -----
__global__ __launch_bounds__(128)
void k1b_reduce(float* __restrict__ ws, int PB) {
    const int S = 8;
    const int chunk = blockIdx.x % 33;
    const int rem   = blockIdx.x / 33;
    const int b     = rem & 1;
    const int slice = rem >> 1;
    const int j = chunk * 128 + threadIdx.x;       // [0, 4224)
    const int PBh = PB >> 1;
    const float* part = ws + WS_PART;
    float s = 0.f;
    for (int pi = b * PBh + slice; pi < (b + 1) * PBh; pi += S)
        s += part[(long)pi * PART_STRIDE + j];
    float* dst = (j < 4096) ? (ws + WS_CTX + b * 4096 + j)
                            : (ws + WS_RS + b * 128 + (j - 4096));
    atomicAdd(dst, s);
}

// ---------------- K2: ATb[up][o] = packed bf16 pair of A^T ---------------
__global__ __launch_bounds__(256)
void k2_prepA(const float* __restrict__ wout, float* __restrict__ ws) {
    __shared__ float wo[64 * 129];
    __shared__ float ct[4096];
    __shared__ float rsum[128];
    const int b   = blockIdx.x;
    const int tid = threadIdx.x;
    for (int i = tid; i < 8192; i += 256) wo[(i >> 7) * 129 + (i & 127)] = wout[i];
    for (int i = tid; i < 4096; i += 256) ct[i] = ws[WS_CTX + b * 4096 + i];
    if (tid < 128) rsum[tid] = ws[WS_RS + b * 128 + tid];
    __syncthreads();
    u32* atb = (u32*)ws + WS_ATB + b * 4096;
    const int o  = tid & 63;
    const int ug = tid >> 6;
    for (int i = 0; i < 16; ++i) {
        const int up = ug * 16 + i;
        const int hc0 = 2 * up, hc1 = 2 * up + 1;
        const int hh = hc0 >> 5;
        const int c0 = hc0 & 31, c1 = hc1 & 31;
        float s0 = 0.f, s1 = 0.f;
        #pragma unroll
        for (int d = 0; d < 32; ++d) {
            const float w = wo[o * 129 + hh * 32 + d];
            s0 = fmaf(w, ct[hh * 1024 + c0 * 32 + d], s0);
            s1 = fmaf(w, ct[hh * 1024 + c1 * 32 + d], s1);
        }
        atb[up * 64 + o] = pk2(s0 / rsum[hc0], s1 / rsum[hc1]);
    }
}

// ---------------- K3: q GEMM (MFMA) + in-reg softmax + A@q (MFMA) --------
// R8 kernel; qb softmax stores fused to uint2 (same bytes, 2 b64 vs 8 u16).
__global__ __launch_bounds__(256, 2)
void k3_out(const float* __restrict__ x, const float* __restrict__ wq,
            const float* __restrict__ bout, const float* __restrict__ wsf,
            float* __restrict__ out) {
    __shared__ u32 xbh[64 * 32];       // 8 KB
    __shared__ u32 xbl[64 * 32];       // 8 KB
    __shared__ u16 qb[64 * 128];       // [px][hc] bf16, swizzled, 16 KB
    const int blk  = blockIdx.x;
    const int b    = blk / NTILES;
    const int tile = blk % NTILES;
    const long i0  = (long)tile * 64;
    const int p    = threadIdx.x & 63;
    const int og   = __builtin_amdgcn_readfirstlane(threadIdx.x >> 6);
    const int q    = p >> 4;
    const int l15  = p & 15;
    const int yv   = (p & 7) << 2;
    const float* xg = x + (long)b * 64 * NPIX;

    // x loads first (coalesced, longest latency)
    float xl[16];
    {
        const float* xr = xg + (long)(og * 16) * NPIX + i0 + p;
        #pragma unroll
        for (int i = 0; i < 16; ++i) xl[i] = xr[(long)i * NPIX];
    }

    // W frags: q rows og*32..+32, split
    FragU wh[2][2], wl[2][2];
    #pragma unroll
    for (int mi = 0; mi < 2; ++mi)
        #pragma unroll
        for (int ks = 0; ks < 2; ++ks) {
            const int row = og * 32 + mi * 16 + l15;
            const float* wp = wq + row * 64 + ks * 32 + q * 4;
            float4 f0 = *(const float4*)wp;
            float4 f1 = *(const float4*)(wp + 16);
            split2(f0.x, f0.y, wh[mi][ks].u[0], wl[mi][ks].u[0]);
            split2(f0.z, f0.w, wh[mi][ks].u[1], wl[mi][ks].u[1]);
            split2(f1.x, f1.y, wh[mi][ks].u[2], wl[mi][ks].u[2]);
            split2(f1.z, f1.w, wh[mi][ks].u[3], wl[mi][ks].u[3]);
        }

    // ATb frags (per-b matrix, packed bf16 pairs)
    const u32* atb = (const u32*)wsf + WS_ATB + b * 4096;
    FragU af[4];
    #pragma unroll
    for (int ks = 0; ks < 4; ++ks) {
        const int up0 = ks * 16 + 2 * q;
        const int o   = og * 16 + l15;
        af[ks].u[0] = atb[(up0)     * 64 + o];
        af[ks].u[1] = atb[(up0 + 1) * 64 + o];
        af[ks].u[2] = atb[(up0 + 8) * 64 + o];
        af[ks].u[3] = atb[(up0 + 9) * 64 + o];
    }
    const float4 bias = *(const float4*)&bout[og * 16 + q * 4];

    // transpose-pack xl -> split bf16
    {
        u32 hb_[8], lb_[8];
        #pragma unroll
        for (int w = 0; w < 8; ++w) split2(xl[2 * w], xl[2 * w + 1], hb_[w], lb_[w]);
        const int yy = (p & 7) << 2;
        const int sA = (og * 8) ^ yy;
        const int sB = (og * 8 + 4) ^ yy;
        *(uint4*)&xbh[p * 32 + sA] = make_uint4(hb_[0], hb_[1], hb_[2], hb_[3]);
        *(uint4*)&xbh[p * 32 + sB] = make_uint4(hb_[4], hb_[5], hb_[6], hb_[7]);
        *(uint4*)&xbl[p * 32 + sA] = make_uint4(lb_[0], lb_[1], lb_[2], lb_[3]);
        *(uint4*)&xbl[p * 32 + sB] = make_uint4(lb_[4], lb_[5], lb_[6], lb_[7]);
    }
    __syncthreads();

    // phase 1 + softmax, per px-block ni
    #pragma unroll
    for (int ni = 0; ni < 4; ++ni) {
        const int rb = (ni * 16 + l15) * 32;
        FragU bh[2], bl[2];
        #pragma unroll
        for (int ks = 0; ks < 2; ++ks) {
            const int c0 = (ks * 16 + 2 * q) ^ yv;
            const int c1 = (ks * 16 + 2 * q + 8) ^ yv;
            uint2 t0 = *(const uint2*)&xbh[rb + c0];
            uint2 t1 = *(const uint2*)&xbh[rb + c1];
            bh[ks].u[0] = t0.x; bh[ks].u[1] = t0.y;
            bh[ks].u[2] = t1.x; bh[ks].u[3] = t1.y;
            uint2 s0 = *(const uint2*)&xbl[rb + c0];
            uint2 s1 = *(const uint2*)&xbl[rb + c1];
            bl[ks].u[0] = s0.x; bl[ks].u[1] = s0.y;
            bl[ks].u[2] = s1.x; bl[ks].u[3] = s1.y;
        }
        f32x4 a0 = (f32x4)0.f, a1 = (f32x4)0.f;
        #pragma unroll
        for (int ks = 0; ks < 2; ++ks) {
            a0 = MFMA(wh[0][ks].v, bh[ks].v, a0);
            a0 = MFMA(wh[0][ks].v, bl[ks].v, a0);
            a0 = MFMA(wl[0][ks].v, bh[ks].v, a0);
            a1 = MFMA(wh[1][ks].v, bh[ks].v, a1);
            a1 = MFMA(wh[1][ks].v, bl[ks].v, a1);
            a1 = MFMA(wl[1][ks].v, bh[ks].v, a1);
        }
        // softmax over head og's 32 rows for this lane's px column
        float mx = a0[0];
        #pragma unroll
        for (int j = 1; j < 4; ++j) mx = fmaxf(mx, a0[j]);
        #pragma unroll
        for (int j = 0; j < 4; ++j) mx = fmaxf(mx, a1[j]);
        mx = fmaxf(mx, __shfl_xor(mx, 16));
        mx = fmaxf(mx, __shfl_xor(mx, 32));
        float e0[4], e1[4], sm = 0.f;
        #pragma unroll
        for (int j = 0; j < 4; ++j) { e0[j] = __expf(a0[j] - mx); sm += e0[j]; }
        #pragma unroll
        for (int j = 0; j < 4; ++j) { e1[j] = __expf(a1[j] - mx); sm += e1[j]; }
        sm += __shfl_xor(sm, 16);
        sm += __shfl_xor(sm, 32);
        const float inv = 1.0f / sm;
        const int px = ni * 16 + l15;
        const int Xq = (px & 7) << 3;              // u16-unit swizzle (as before)
        u32* qbw = (u32*)qb;
        const int b0 = (px * 128 + ((og * 32 + q * 4) ^ Xq)) >> 1;
        const int b1 = (px * 128 + ((og * 32 + 16 + q * 4) ^ Xq)) >> 1;
        *(uint2*)&qbw[b0] = make_uint2(pk2(e0[0] * inv, e0[1] * inv),
                                       pk2(e0[2] * inv, e0[3] * inv));
        *(uint2*)&qbw[b1] = make_uint2(pk2(e1[0] * inv, e1[1] * inv),
                                       pk2(e1[2] * inv, e1[3] * inv));
    }
    __syncthreads();

    // phase 3: out = A^T qsm + bias
    const u32* qb32 = (const u32*)qb;
    #pragma unroll
    for (int ni = 0; ni < 4; ++ni) {
        const int px = ni * 16 + l15;
        const int rb = px * 64;
        f32x4 a3 = (f32x4)0.f;
        #pragma unroll
        for (int ks = 0; ks < 4; ++ks) {
            const int c0 = (ks * 16 + 2 * q) ^ yv;
            const int c1 = (ks * 16 + 2 * q + 8) ^ yv;
            uint2 t0 = *(const uint2*)&qb32[rb + c0];
            uint2 t1 = *(const uint2*)&qb32[rb + c1];
            FragU bq;
            bq.u[0] = t0.x; bq.u[1] = t0.y; bq.u[2] = t1.x; bq.u[3] = t1.y;
            a3 = MFMA(af[ks].v, bq.v, a3);
        }
        #pragma unroll
        for (int j = 0; j < 4; ++j)
            out[((long)b * 64 + og * 16 + q * 4 + j) * NPIX + i0 + px] = a3[j] + bias[j];
    }
}

extern "C" void kernel_launch(void* const* d_in, const int* in_sizes, int n_in,
                              void* d_out, int out_size, void* d_ws, size_t ws_size,
                              hipStream_t stream) {
    (void)in_sizes; (void)n_in; (void)out_size;
    const float* x     = (const float*)d_in[0];
    const float* w_qkv = (const float*)d_in[1];
    const float* w_out = (const float*)d_in[2];
    const float* b_out = (const float*)d_in[3];
    float* out = (float*)d_out;
    float* ws  = (float*)d_ws;

    const size_t need_part = ((size_t)WS_PART + (size_t)K1_BLOCKS * PART_STRIDE) * 4;
    const int usePart = (ws_size >= need_part) ? 1 : 0;
    int R = 8;
    const size_t need_r8 = ((size_t)WS_PART + (size_t)2 * 8 * PART_STRIDE) * 4;
    if (!usePart && ws_size < need_r8) R = 1;
    const int PB = usePart ? K1_BLOCKS : 2 * R;
    float* part = ws + WS_PART;

    if (!usePart)
        hipMemsetAsync(part, 0, (size_t)PB * PART_STRIDE * 4, stream);
    hipLaunchKernelGGL(k1_ctx, dim3(K1_BLOCKS), dim3(256), 0, stream,
                       x, w_qkv, part, usePart, R);
    hipMemsetAsync(ws + WS_CTX, 0, (size_t)(2 * PART_STRIDE) * 4, stream);
    hipLaunchKernelGGL(k1b_reduce, dim3(528), dim3(128), 0, stream, ws, PB);
    hipLaunchKernelGGL(k2_prepA, dim3(2), dim3(256), 0, stream, w_out, ws);
    hipLaunchKernelGGL(k3_out, dim3(2 * NTILES), dim3(256), 0, stream,
                       x, w_qkv, b_out, ws, out);
}

// Round 10
// 103.521 us; speedup vs baseline: 1.0296x; 1.0296x over previous
//
#include <hip/hip_runtime.h>

typedef unsigned int u32;
typedef unsigned short u16;
typedef __attribute__((ext_vector_type(8))) short bf16x8;   // 8 bf16 in 4 VGPRs
typedef __attribute__((ext_vector_type(4))) float f32x4;

#define NPIX 110592            // 48^3
#define NTILES 1728            // NPIX/64 per batch
#define K1_BLOCKS 864          // each block: 4 tiles, b-aligned
#define K1_TPB 4
#define PART_STRIDE 4224       // 4096 ctx + 128 rowsum

// ws layout (4-byte slots)
#define WS_CTX   0             // 2*4096 f32
#define WS_RS    8192          // 2*128 f32
#define WS_ATB   8448          // 2*4096 u32 (packed bf16 pairs of A^T)
#define WS_PART  16640

union FragU { u32 u[4]; bf16x8 v; };

#define MFMA(a,b,c) __builtin_amdgcn_mfma_f32_16x16x32_bf16((a),(b),(c),0,0,0)

__device__ __forceinline__ u32 f2bf(float f) {            // RNE f32->bf16 bits
    u32 u = __float_as_uint(f);
    return (u + 0x7FFFu + ((u >> 16) & 1u)) >> 16;
}
__device__ __forceinline__ float bf2f(u32 bits) { return __uint_as_float(bits << 16); }
__device__ __forceinline__ u32 pk2(float a, float b) { return f2bf(a) | (f2bf(b) << 16); }
__device__ __forceinline__ void split2(float a, float b, u32& hi, u32& lo) {
    u32 ha = f2bf(a), hb = f2bf(b);
    hi = ha | (hb << 16);
    lo = pk2(a - bf2f(ha), b - bf2f(hb));
}

// ---------------- K1: k,v GEMM (MFMA) + ctx/rowsum (MFMA) ----------------
// R9 numerics; structural changes: (a) xt/gll dropped -> direct reg x-loads,
// LDS 48 KB -> 3 blocks/CU; (b) wave og computes exactly the kv rows its
// phase 2 consumes (K: og*32..+32, V: 128+og*32..+32) -> kvb is wave-private,
// no barriers around it; only xb keeps 2 barriers/tile.
__global__ __launch_bounds__(256, 2)
void k1_ctx(const float* __restrict__ x, const float* __restrict__ wq,
            float* __restrict__ part, int usePart, int R) {
    __shared__ u32   xbh[64 * 32];     // [px][cpair hi], swizzled, 8 KB
    __shared__ u32   xbl[64 * 32];     // [px][cpair lo], 8 KB
    __shared__ u32   kvb[256 * 32];    // [row][px-pair] bf16, swizzled, 32 KB
    const int blk = blockIdx.x;
    const int p   = threadIdx.x & 63;
    const int og  = __builtin_amdgcn_readfirstlane(threadIdx.x >> 6);
    const int b   = blk / (K1_BLOCKS / 2);
    const int q   = p >> 4;
    const int l15 = p & 15;
    const int yv  = (p & 7) << 2;
    const float* xg = x + (long)b * 64 * NPIX;

    // kv rows this wave produces AND consumes: mi<2 -> K rows og*32+mi*16,
    // mi>=2 -> V rows 128+og*32+(mi-2)*16. W row = 128 + kvrow.
    FragU wh[4][2], wl[4][2];
    #pragma unroll
    for (int mi = 0; mi < 4; ++mi)
        #pragma unroll
        for (int ks = 0; ks < 2; ++ks) {
            const int kvrow = (mi < 2) ? (og * 32 + mi * 16) : (128 + og * 32 + (mi - 2) * 16);
            const int row = 128 + kvrow + l15;
            const float* wp = wq + row * 64 + ks * 32 + q * 4;
            float4 f0 = *(const float4*)wp;
            float4 f1 = *(const float4*)(wp + 16);
            split2(f0.x, f0.y, wh[mi][ks].u[0], wl[mi][ks].u[0]);
            split2(f0.z, f0.w, wh[mi][ks].u[1], wl[mi][ks].u[1]);
            split2(f1.x, f1.y, wh[mi][ks].u[2], wl[mi][ks].u[2]);
            split2(f1.z, f1.w, wh[mi][ks].u[3], wl[mi][ks].u[3]);
        }

    FragU ones;
    #pragma unroll
    for (int i = 0; i < 4; ++i) ones.u[i] = 0x3F803F80u;

    f32x4 cc[2][2], rsa[2];
    #pragma unroll
    for (int mi = 0; mi < 2; ++mi) {
        #pragma unroll
        for (int ni = 0; ni < 2; ++ni) cc[mi][ni] = (f32x4)0.f;
        rsa[mi] = (f32x4)0.f;
    }

    // x for this thread: c rows og*16..+16, column i0+p (coalesced)
    float xl[16];
    {
        const long i0 = (long)(blk * K1_TPB - b * NTILES) * 64;
        const float* xr = xg + (long)(og * 16) * NPIX + i0 + p;
        #pragma unroll
        for (int i = 0; i < 16; ++i) xl[i] = xr[(long)i * NPIX];
    }

    #pragma unroll 1
    for (int tt = 0; tt < K1_TPB; ++tt) {
        // pack xl -> split bf16 xb (this thread: px=p, c-pairs og*8..+8)
        {
            u32 hb_[8], lb_[8];
            #pragma unroll
            for (int w = 0; w < 8; ++w) split2(xl[2 * w], xl[2 * w + 1], hb_[w], lb_[w]);
            const int yy = (p & 7) << 2;
            const int sA = (og * 8) ^ yy;
            const int sB = (og * 8 + 4) ^ yy;
            *(uint4*)&xbh[p * 32 + sA] = make_uint4(hb_[0], hb_[1], hb_[2], hb_[3]);
            *(uint4*)&xbh[p * 32 + sB] = make_uint4(hb_[4], hb_[5], hb_[6], hb_[7]);
            *(uint4*)&xbl[p * 32 + sA] = make_uint4(lb_[0], lb_[1], lb_[2], lb_[3]);
            *(uint4*)&xbl[p * 32 + sB] = make_uint4(lb_[4], lb_[5], lb_[6], lb_[7]);
        }
        __syncthreads();               // xb ready

        // phase 1: D[px][o] via MFMA(x_frag, w_frag); epilogue b64 stores
        // into this wave's own kvb rows.
        #pragma unroll
        for (int ni = 0; ni < 4; ++ni) {
            const int rb = (ni * 16 + l15) * 32;
            FragU bh[2], bl[2];
            #pragma unroll
            for (int ks = 0; ks < 2; ++ks) {
                const int c0 = (ks * 16 + 2 * q) ^ yv;
                const int c1 = (ks * 16 + 2 * q + 8) ^ yv;
                uint2 t0 = *(const uint2*)&xbh[rb + c0];
                uint2 t1 = *(const uint2*)&xbh[rb + c1];
                bh[ks].u[0] = t0.x; bh[ks].u[1] = t0.y;
                bh[ks].u[2] = t1.x; bh[ks].u[3] = t1.y;
                uint2 s0 = *(const uint2*)&xbl[rb + c0];
                uint2 s1 = *(const uint2*)&xbl[rb + c1];
                bl[ks].u[0] = s0.x; bl[ks].u[1] = s0.y;
                bl[ks].u[2] = s1.x; bl[ks].u[3] = s1.y;
            }
            #pragma unroll
            for (int mi = 0; mi < 4; ++mi) {
                f32x4 acc = (f32x4)0.f;
                #pragma unroll
                for (int ks = 0; ks < 2; ++ks) {
                    acc = MFMA(bh[ks].v, wh[mi][ks].v, acc);
                    acc = MFMA(bl[ks].v, wh[mi][ks].v, acc);
                    acc = MFMA(bh[ks].v, wl[mi][ks].v, acc);
                }
                const int kvrow = (mi < 2) ? (og * 32 + mi * 16) : (128 + og * 32 + (mi - 2) * 16);
                const int row = kvrow + l15;
                const int X   = ((row >> 2) & 7) << 2;
                float v0 = acc[0], v1 = acc[1], v2 = acc[2], v3 = acc[3];
                if (mi < 2) {
                    v0 = __expf(v0); v1 = __expf(v1);
                    v2 = __expf(v2); v3 = __expf(v3);
                }
                const int pair0 = ni * 8 + q * 2;
                *(uint2*)&kvb[row * 32 + (pair0 ^ X)] =
                    make_uint2(pk2(v0, v1), pk2(v2, v3));
            }
        }
        __syncthreads();               // xb consumed (next pack may overwrite)

        if (tt + 1 < K1_TPB) {         // next tile's x, overlaps phase 2
            const long i0 = (long)(blk * K1_TPB + tt + 1 - b * NTILES) * 64;
            const float* xr = xg + (long)(og * 16) * NPIX + i0 + p;
            #pragma unroll
            for (int i = 0; i < 16; ++i) xl[i] = xr[(long)i * NPIX];
        }

        // phase 2: ctx(32x32) += EK x V^T, rowsum via B=ones.
        // Reads ONLY this wave's own kvb rows -> no barrier needed.
        const int hb0 = og * 32;
        const int hb1 = 128 + og * 32;
        #pragma unroll
        for (int ksp = 0; ksp < 2; ++ksp) {
            FragU ak[2], av[2];
            #pragma unroll
            for (int mi = 0; mi < 2; ++mi) {
                {
                    const int row = hb0 + mi * 16 + l15;
                    const int Xr = ((row >> 2) & 7) << 2;
                    const int p0 = (ksp * 16 + 2 * q) ^ Xr;
                    const int p1 = (ksp * 16 + 2 * q + 8) ^ Xr;
                    uint2 t0 = *(const uint2*)&kvb[row * 32 + p0];
                    uint2 t1 = *(const uint2*)&kvb[row * 32 + p1];
                    ak[mi].u[0] = t0.x; ak[mi].u[1] = t0.y;
                    ak[mi].u[2] = t1.x; ak[mi].u[3] = t1.y;
                }
                {
                    const int row = hb1 + mi * 16 + l15;
                    const int Xr = ((row >> 2) & 7) << 2;
                    const int p0 = (ksp * 16 + 2 * q) ^ Xr;
                    const int p1 = (ksp * 16 + 2 * q + 8) ^ Xr;
                    uint2 t0 = *(const uint2*)&kvb[row * 32 + p0];
                    uint2 t1 = *(const uint2*)&kvb[row * 32 + p1];
                    av[mi].u[0] = t0.x; av[mi].u[1] = t0.y;
                    av[mi].u[2] = t1.x; av[mi].u[3] = t1.y;
                }
            }
            #pragma unroll
            for (int mi = 0; mi < 2; ++mi) {
                #pragma unroll
                for (int ni = 0; ni < 2; ++ni)
                    cc[mi][ni] = MFMA(ak[mi].v, av[ni].v, cc[mi][ni]);
                rsa[mi] = MFMA(ak[mi].v, ones.v, rsa[mi]);
            }
        }
    }

    // epilogue: per-block partials (or atomic replicas) — unchanged
    if (usePart) {
        float* pp = part + (long)blk * PART_STRIDE;
        #pragma unroll
        for (int mi = 0; mi < 2; ++mi)
            #pragma unroll
            for (int ni = 0; ni < 2; ++ni)
                #pragma unroll
                for (int j = 0; j < 4; ++j)
                    pp[og * 1024 + (mi * 16 + q * 4 + j) * 32 + ni * 16 + l15] = cc[mi][ni][j];
        if (l15 == 0) {
            #pragma unroll
            for (int mi = 0; mi < 2; ++mi)
                #pragma unroll
                for (int j = 0; j < 4; ++j)
                    pp[4096 + og * 32 + mi * 16 + q * 4 + j] = rsa[mi][j];
        }
    } else {
        float* pp = part + (long)(b * R + (blk % R)) * PART_STRIDE;
        #pragma unroll
        for (int mi = 0; mi < 2; ++mi)
            #pragma unroll
            for (int ni = 0; ni < 2; ++ni)
                #pragma unroll
                for (int j = 0; j < 4; ++j)
                    atomicAdd(&pp[og * 1024 + (mi * 16 + q * 4 + j) * 32 + ni * 16 + l15], cc[mi][ni][j]);
        if (l15 == 0) {
            #pragma unroll
            for (int mi = 0; mi < 2; ++mi)
                #pragma unroll
                for (int j = 0; j < 4; ++j)
                    atomicAdd(&pp[4096 + og * 32 + mi * 16 + q * 4 + j], rsa[mi][j]);
        }
    }
}

// ---------------- K1b: reduce partials -> ctx, rsum (atomic, sliced) -----
__global__ __launch_bounds__(128)
void k1b_reduce(float* __restrict__ ws, int PB) {
    const int S = 8;
    const int chunk = blockIdx.x % 33;
    const int rem   = blockIdx.x / 33;
    const int b     = rem & 1;
    const int slice = rem >> 1;
    const int j = chunk * 128 + threadIdx.x;       // [0, 4224)
    const int PBh = PB >> 1;
    const float* part = ws + WS_PART;
    float s = 0.f;
    for (int pi = b * PBh + slice; pi < (b + 1) * PBh; pi += S)
        s += part[(long)pi * PART_STRIDE + j];
    float* dst = (j < 4096) ? (ws + WS_CTX + b * 4096 + j)
                            : (ws + WS_RS + b * 128 + (j - 4096));
    atomicAdd(dst, s);
}

// ---------------- K2: ATb[up][o] = packed bf16 pair of A^T ---------------
__global__ __launch_bounds__(256)
void k2_prepA(const float* __restrict__ wout, float* __restrict__ ws) {
    __shared__ float wo[64 * 129];
    __shared__ float ct[4096];
    __shared__ float rsum[128];
    const int b   = blockIdx.x;
    const int tid = threadIdx.x;
    for (int i = tid; i < 8192; i += 256) wo[(i >> 7) * 129 + (i & 127)] = wout[i];
    for (int i = tid; i < 4096; i += 256) ct[i] = ws[WS_CTX + b * 4096 + i];
    if (tid < 128) rsum[tid] = ws[WS_RS + b * 128 + tid];
    __syncthreads();
    u32* atb = (u32*)ws + WS_ATB + b * 4096;
    const int o  = tid & 63;
    const int ug = tid >> 6;
    for (int i = 0; i < 16; ++i) {
        const int up = ug * 16 + i;
        const int hc0 = 2 * up, hc1 = 2 * up + 1;
        const int hh = hc0 >> 5;
        const int c0 = hc0 & 31, c1 = hc1 & 31;
        float s0 = 0.f, s1 = 0.f;
        #pragma unroll
        for (int d = 0; d < 32; ++d) {
            const float w = wo[o * 129 + hh * 32 + d];
            s0 = fmaf(w, ct[hh * 1024 + c0 * 32 + d], s0);
            s1 = fmaf(w, ct[hh * 1024 + c1 * 32 + d], s1);
        }
        atb[up * 64 + o] = pk2(s0 / rsum[hc0], s1 / rsum[hc1]);
    }
}

// ---------------- K3: q GEMM (MFMA) + in-reg softmax + A@q (MFMA) --------
// R9 kernel verbatim.
__global__ __launch_bounds__(256, 2)
void k3_out(const float* __restrict__ x, const float* __restrict__ wq,
            const float* __restrict__ bout, const float* __restrict__ wsf,
            float* __restrict__ out) {
    __shared__ u32 xbh[64 * 32];       // 8 KB
    __shared__ u32 xbl[64 * 32];       // 8 KB
    __shared__ u16 qb[64 * 128];       // [px][hc] bf16, swizzled, 16 KB
    const int blk  = blockIdx.x;
    const int b    = blk / NTILES;
    const int tile = blk % NTILES;
    const long i0  = (long)tile * 64;
    const int p    = threadIdx.x & 63;
    const int og   = __builtin_amdgcn_readfirstlane(threadIdx.x >> 6);
    const int q    = p >> 4;
    const int l15  = p & 15;
    const int yv   = (p & 7) << 2;
    const float* xg = x + (long)b * 64 * NPIX;

    // x loads first (coalesced, longest latency)
    float xl[16];
    {
        const float* xr = xg + (long)(og * 16) * NPIX + i0 + p;
        #pragma unroll
        for (int i = 0; i < 16; ++i) xl[i] = xr[(long)i * NPIX];
    }

    // W frags: q rows og*32..+32, split
    FragU wh[2][2], wl[2][2];
    #pragma unroll
    for (int mi = 0; mi < 2; ++mi)
        #pragma unroll
        for (int ks = 0; ks < 2; ++ks) {
            const int row = og * 32 + mi * 16 + l15;
            const float* wp = wq + row * 64 + ks * 32 + q * 4;
            float4 f0 = *(const float4*)wp;
            float4 f1 = *(const float4*)(wp + 16);
            split2(f0.x, f0.y, wh[mi][ks].u[0], wl[mi][ks].u[0]);
            split2(f0.z, f0.w, wh[mi][ks].u[1], wl[mi][ks].u[1]);
            split2(f1.x, f1.y, wh[mi][ks].u[2], wl[mi][ks].u[2]);
            split2(f1.z, f1.w, wh[mi][ks].u[3], wl[mi][ks].u[3]);
        }

    // ATb frags (per-b matrix, packed bf16 pairs)
    const u32* atb = (const u32*)wsf + WS_ATB + b * 4096;
    FragU af[4];
    #pragma unroll
    for (int ks = 0; ks < 4; ++ks) {
        const int up0 = ks * 16 + 2 * q;
        const int o   = og * 16 + l15;
        af[ks].u[0] = atb[(up0)     * 64 + o];
        af[ks].u[1] = atb[(up0 + 1) * 64 + o];
        af[ks].u[2] = atb[(up0 + 8) * 64 + o];
        af[ks].u[3] = atb[(up0 + 9) * 64 + o];
    }
    const float4 bias = *(const float4*)&bout[og * 16 + q * 4];

    // transpose-pack xl -> split bf16
    {
        u32 hb_[8], lb_[8];
        #pragma unroll
        for (int w = 0; w < 8; ++w) split2(xl[2 * w], xl[2 * w + 1], hb_[w], lb_[w]);
        const int yy = (p & 7) << 2;
        const int sA = (og * 8) ^ yy;
        const int sB = (og * 8 + 4) ^ yy;
        *(uint4*)&xbh[p * 32 + sA] = make_uint4(hb_[0], hb_[1], hb_[2], hb_[3]);
        *(uint4*)&xbh[p * 32 + sB] = make_uint4(hb_[4], hb_[5], hb_[6], hb_[7]);
        *(uint4*)&xbl[p * 32 + sA] = make_uint4(lb_[0], lb_[1], lb_[2], lb_[3]);
        *(uint4*)&xbl[p * 32 + sB] = make_uint4(lb_[4], lb_[5], lb_[6], lb_[7]);
    }
    __syncthreads();

    // phase 1 + softmax, per px-block ni
    #pragma unroll
    for (int ni = 0; ni < 4; ++ni) {
        const int rb = (ni * 16 + l15) * 32;
        FragU bh[2], bl[2];
        #pragma unroll
        for (int ks = 0; ks < 2; ++ks) {
            const int c0 = (ks * 16 + 2 * q) ^ yv;
            const int c1 = (ks * 16 + 2 * q + 8) ^ yv;
            uint2 t0 = *(const uint2*)&xbh[rb + c0];
            uint2 t1 = *(const uint2*)&xbh[rb + c1];
            bh[ks].u[0] = t0.x; bh[ks].u[1] = t0.y;
            bh[ks].u[2] = t1.x; bh[ks].u[3] = t1.y;
            uint2 s0 = *(const uint2*)&xbl[rb + c0];
            uint2 s1 = *(const uint2*)&xbl[rb + c1];
            bl[ks].u[0] = s0.x; bl[ks].u[1] = s0.y;
            bl[ks].u[2] = s1.x; bl[ks].u[3] = s1.y;
        }
        f32x4 a0 = (f32x4)0.f, a1 = (f32x4)0.f;
        #pragma unroll
        for (int ks = 0; ks < 2; ++ks) {
            a0 = MFMA(wh[0][ks].v, bh[ks].v, a0);
            a0 = MFMA(wh[0][ks].v, bl[ks].v, a0);
            a0 = MFMA(wl[0][ks].v, bh[ks].v, a0);
            a1 = MFMA(wh[1][ks].v, bh[ks].v, a1);
            a1 = MFMA(wh[1][ks].v, bl[ks].v, a1);
            a1 = MFMA(wl[1][ks].v, bh[ks].v, a1);
        }
        // softmax over head og's 32 rows for this lane's px column
        float mx = a0[0];
        #pragma unroll
        for (int j = 1; j < 4; ++j) mx = fmaxf(mx, a0[j]);
        #pragma unroll
        for (int j = 0; j < 4; ++j) mx = fmaxf(mx, a1[j]);
        mx = fmaxf(mx, __shfl_xor(mx, 16));
        mx = fmaxf(mx, __shfl_xor(mx, 32));
        float e0[4], e1[4], sm = 0.f;
        #pragma unroll
        for (int j = 0; j < 4; ++j) { e0[j] = __expf(a0[j] - mx); sm += e0[j]; }
        #pragma unroll
        for (int j = 0; j < 4; ++j) { e1[j] = __expf(a1[j] - mx); sm += e1[j]; }
        sm += __shfl_xor(sm, 16);
        sm += __shfl_xor(sm, 32);
        const float inv = 1.0f / sm;
        const int px = ni * 16 + l15;
        const int Xq = (px & 7) << 3;              // u16-unit swizzle (as before)
        u32* qbw = (u32*)qb;
        const int b0 = (px * 128 + ((og * 32 + q * 4) ^ Xq)) >> 1;
        const int b1 = (px * 128 + ((og * 32 + 16 + q * 4) ^ Xq)) >> 1;
        *(uint2*)&qbw[b0] = make_uint2(pk2(e0[0] * inv, e0[1] * inv),
                                       pk2(e0[2] * inv, e0[3] * inv));
        *(uint2*)&qbw[b1] = make_uint2(pk2(e1[0] * inv, e1[1] * inv),
                                       pk2(e1[2] * inv, e1[3] * inv));
    }
    __syncthreads();

    // phase 3: out = A^T qsm + bias
    const u32* qb32 = (const u32*)qb;
    #pragma unroll
    for (int ni = 0; ni < 4; ++ni) {
        const int px = ni * 16 + l15;
        const int rb = px * 64;
        f32x4 a3 = (f32x4)0.f;
        #pragma unroll
        for (int ks = 0; ks < 4; ++ks) {
            const int c0 = (ks * 16 + 2 * q) ^ yv;
            const int c1 = (ks * 16 + 2 * q + 8) ^ yv;
            uint2 t0 = *(const uint2*)&qb32[rb + c0];
            uint2 t1 = *(const uint2*)&qb32[rb + c1];
            FragU bq;
            bq.u[0] = t0.x; bq.u[1] = t0.y; bq.u[2] = t1.x; bq.u[3] = t1.y;
            a3 = MFMA(af[ks].v, bq.v, a3);
        }
        #pragma unroll
        for (int j = 0; j < 4; ++j)
            out[((long)b * 64 + og * 16 + q * 4 + j) * NPIX + i0 + px] = a3[j] + bias[j];
    }
}

extern "C" void kernel_launch(void* const* d_in, const int* in_sizes, int n_in,
                              void* d_out, int out_size, void* d_ws, size_t ws_size,
                              hipStream_t stream) {
    (void)in_sizes; (void)n_in; (void)out_size;
    const float* x     = (const float*)d_in[0];
    const float* w_qkv = (const float*)d_in[1];
    const float* w_out = (const float*)d_in[2];
    const float* b_out = (const float*)d_in[3];
    float* out = (float*)d_out;
    float* ws  = (float*)d_ws;

    const size_t need_part = ((size_t)WS_PART + (size_t)K1_BLOCKS * PART_STRIDE) * 4;
    const int usePart = (ws_size >= need_part) ? 1 : 0;
    int R = 8;
    const size_t need_r8 = ((size_t)WS_PART + (size_t)2 * 8 * PART_STRIDE) * 4;
    if (!usePart && ws_size < need_r8) R = 1;
    const int PB = usePart ? K1_BLOCKS : 2 * R;
    float* part = ws + WS_PART;

    if (!usePart)
        hipMemsetAsync(part, 0, (size_t)PB * PART_STRIDE * 4, stream);
    hipLaunchKernelGGL(k1_ctx, dim3(K1_BLOCKS), dim3(256), 0, stream,
                       x, w_qkv, part, usePart, R);
    hipMemsetAsync(ws + WS_CTX, 0, (size_t)(2 * PART_STRIDE) * 4, stream);
    hipLaunchKernelGGL(k1b_reduce, dim3(528), dim3(128), 0, stream, ws, PB);
    hipLaunchKernelGGL(k2_prepA, dim3(2), dim3(256), 0, stream, w_out, ws);
    hipLaunchKernelGGL(k3_out, dim3(2 * NTILES), dim3(256), 0, stream,
                       x, w_qkv, b_out, ws, out);
}

// Round 11
// 100.630 us; speedup vs baseline: 1.0592x; 1.0287x over previous
//
#include <hip/hip_runtime.h>

typedef unsigned int u32;
typedef unsigned short u16;
typedef __attribute__((ext_vector_type(8))) short bf16x8;   // 8 bf16 in 4 VGPRs
typedef __attribute__((ext_vector_type(4))) float f32x4;

#define NPIX 110592            // 48^3
#define NTILES 1728            // NPIX/64 per batch
#define K1_BLOCKS 864          // each block: one 256-px group (4 tiles), b-aligned
#define K1_TPB 4
#define PART_STRIDE 4224       // 4096 ctx + 128 rowsum

// ws layout (4-byte slots)
#define WS_CTX   0             // 2*4096 f32
#define WS_RS    8192          // 2*128 f32
#define WS_ATB   8448          // 2*4096 u32 (packed bf16 pairs of A^T)
#define WS_PART  16640

union FragU { u32 u[4]; bf16x8 v; };

#define MFMA(a,b,c) __builtin_amdgcn_mfma_f32_16x16x32_bf16((a),(b),(c),0,0,0)

__device__ __forceinline__ u32 f2bf(float f) {            // RNE f32->bf16 bits
    u32 u = __float_as_uint(f);
    return (u + 0x7FFFu + ((u >> 16) & 1u)) >> 16;
}
__device__ __forceinline__ float bf2f(u32 bits) { return __uint_as_float(bits << 16); }
__device__ __forceinline__ u32 pk2(float a, float b) { return f2bf(a) | (f2bf(b) << 16); }
__device__ __forceinline__ void split2(float a, float b, u32& hi, u32& lo) {
    u32 ha = f2bf(a), hb = f2bf(b);
    hi = ha | (hb << 16);
    lo = pk2(a - bf2f(ha), b - bf2f(hb));
}

// ---------------- K1: k,v GEMM (MFMA) + ctx/rowsum (MFMA) ----------------
// R11: block = 256-px group. x loaded as float4/lane (64 lanes x 16B = 1KB
// contiguous per c-row -> fixes the 256B-granule HBM pattern that pinned
// R5-R10 at ~870 GB/s). x packed bf16-hi ONLY (xbh 32 KB; split-lo would
// not fit). Pack once per group (2 chunks x 8 rows, 32-VGPR peak). One
// barrier per block. kvb wave-private (R10). Phase1: 4 MFMA/(ni,mi):
// x_hi x (W_hi + W_lo).
__global__ __launch_bounds__(256, 2)
void k1_ctx(const float* __restrict__ x, const float* __restrict__ wq,
            float* __restrict__ part, int usePart, int R) {
    __shared__ u32   xbh[256 * 32];    // [px][cpair hi], swizzled, 32 KB
    __shared__ u32   kvb[256 * 32];    // [row][px-pair] bf16, swizzled, 32 KB
    const int blk = blockIdx.x;
    const int p   = threadIdx.x & 63;
    const int og  = __builtin_amdgcn_readfirstlane(threadIdx.x >> 6);
    const int b   = blk / (K1_BLOCKS / 2);
    const int q   = p >> 4;
    const int l15 = p & 15;
    const int yv  = (p & 7) << 2;
    const float* xg = x + (long)b * 64 * NPIX;

    // kv rows this wave produces AND consumes (R10 mapping)
    FragU wh[4][2], wl[4][2];
    #pragma unroll
    for (int mi = 0; mi < 4; ++mi)
        #pragma unroll
        for (int ks = 0; ks < 2; ++ks) {
            const int kvrow = (mi < 2) ? (og * 32 + mi * 16) : (128 + og * 32 + (mi - 2) * 16);
            const int row = 128 + kvrow + l15;
            const float* wp = wq + row * 64 + ks * 32 + q * 4;
            float4 f0 = *(const float4*)wp;
            float4 f1 = *(const float4*)(wp + 16);
            split2(f0.x, f0.y, wh[mi][ks].u[0], wl[mi][ks].u[0]);
            split2(f0.z, f0.w, wh[mi][ks].u[1], wl[mi][ks].u[1]);
            split2(f1.x, f1.y, wh[mi][ks].u[2], wl[mi][ks].u[2]);
            split2(f1.z, f1.w, wh[mi][ks].u[3], wl[mi][ks].u[3]);
        }

    FragU ones;
    #pragma unroll
    for (int i = 0; i < 4; ++i) ones.u[i] = 0x3F803F80u;

    f32x4 cc[2][2], rsa[2];
    #pragma unroll
    for (int mi = 0; mi < 2; ++mi) {
        #pragma unroll
        for (int ni = 0; ni < 2; ++ni) cc[mi][ni] = (f32x4)0.f;
        rsa[mi] = (f32x4)0.f;
    }

    // ---- stage group's x: 16 rows/wave x 256 px, 1KB/instr, bf16-hi pack
    const long i0g = (long)(blk * K1_TPB - b * NTILES) * 64;   // group px start
    #pragma unroll
    for (int ch = 0; ch < 2; ++ch) {
        f32x4 xl4[8];
        const float* xr = xg + (long)(og * 16 + ch * 8) * NPIX + i0g + 4 * p;
        #pragma unroll
        for (int i = 0; i < 8; ++i) xl4[i] = *(const f32x4*)(xr + (long)i * NPIX);
        #pragma unroll
        for (int j = 0; j < 4; ++j) {
            const int px = 4 * p + j;
            const int yy = (px & 7) << 2;
            u32 h[4];
            #pragma unroll
            for (int w = 0; w < 4; ++w) h[w] = pk2(xl4[2 * w][j], xl4[2 * w + 1][j]);
            const int sA = (og * 8 + ch * 4) ^ yy;
            *(uint4*)&xbh[px * 32 + sA] = make_uint4(h[0], h[1], h[2], h[3]);
        }
    }
    __syncthreads();               // xbh ready for all 4 tiles (read-only after)

    #pragma unroll 1
    for (int tt = 0; tt < K1_TPB; ++tt) {
        // phase 1: D[px][o] via MFMA(x_frag, w_frag); x bf16-hi only
        #pragma unroll
        for (int ni = 0; ni < 4; ++ni) {
            const int rb = (tt * 64 + ni * 16 + l15) * 32;
            FragU bh[2];
            #pragma unroll
            for (int ks = 0; ks < 2; ++ks) {
                const int c0 = (ks * 16 + 2 * q) ^ yv;
                const int c1 = (ks * 16 + 2 * q + 8) ^ yv;
                uint2 t0 = *(const uint2*)&xbh[rb + c0];
                uint2 t1 = *(const uint2*)&xbh[rb + c1];
                bh[ks].u[0] = t0.x; bh[ks].u[1] = t0.y;
                bh[ks].u[2] = t1.x; bh[ks].u[3] = t1.y;
            }
            #pragma unroll
            for (int mi = 0; mi < 4; ++mi) {
                f32x4 acc = (f32x4)0.f;
                #pragma unroll
                for (int ks = 0; ks < 2; ++ks) {
                    acc = MFMA(bh[ks].v, wh[mi][ks].v, acc);
                    acc = MFMA(bh[ks].v, wl[mi][ks].v, acc);
                }
                const int kvrow = (mi < 2) ? (og * 32 + mi * 16) : (128 + og * 32 + (mi - 2) * 16);
                const int row = kvrow + l15;
                const int X   = ((row >> 2) & 7) << 2;
                float v0 = acc[0], v1 = acc[1], v2 = acc[2], v3 = acc[3];
                if (mi < 2) {
                    v0 = __expf(v0); v1 = __expf(v1);
                    v2 = __expf(v2); v3 = __expf(v3);
                }
                const int pair0 = ni * 8 + q * 2;
                *(uint2*)&kvb[row * 32 + (pair0 ^ X)] =
                    make_uint2(pk2(v0, v1), pk2(v2, v3));
            }
        }
        // no barrier: kvb rows are wave-private (R10)

        // phase 2: ctx(32x32) += EK x V^T, rowsum via B=ones
        const int hb0 = og * 32;
        const int hb1 = 128 + og * 32;
        #pragma unroll
        for (int ksp = 0; ksp < 2; ++ksp) {
            FragU ak[2], av[2];
            #pragma unroll
            for (int mi = 0; mi < 2; ++mi) {
                {
                    const int row = hb0 + mi * 16 + l15;
                    const int Xr = ((row >> 2) & 7) << 2;
                    const int p0 = (ksp * 16 + 2 * q) ^ Xr;
                    const int p1 = (ksp * 16 + 2 * q + 8) ^ Xr;
                    uint2 t0 = *(const uint2*)&kvb[row * 32 + p0];
                    uint2 t1 = *(const uint2*)&kvb[row * 32 + p1];
                    ak[mi].u[0] = t0.x; ak[mi].u[1] = t0.y;
                    ak[mi].u[2] = t1.x; ak[mi].u[3] = t1.y;
                }
                {
                    const int row = hb1 + mi * 16 + l15;
                    const int Xr = ((row >> 2) & 7) << 2;
                    const int p0 = (ksp * 16 + 2 * q) ^ Xr;
                    const int p1 = (ksp * 16 + 2 * q + 8) ^ Xr;
                    uint2 t0 = *(const uint2*)&kvb[row * 32 + p0];
                    uint2 t1 = *(const uint2*)&kvb[row * 32 + p1];
                    av[mi].u[0] = t0.x; av[mi].u[1] = t0.y;
                    av[mi].u[2] = t1.x; av[mi].u[3] = t1.y;
                }
            }
            #pragma unroll
            for (int mi = 0; mi < 2; ++mi) {
                #pragma unroll
                for (int ni = 0; ni < 2; ++ni)
                    cc[mi][ni] = MFMA(ak[mi].v, av[ni].v, cc[mi][ni]);
                rsa[mi] = MFMA(ak[mi].v, ones.v, rsa[mi]);
            }
        }
    }

    // epilogue: per-block partials (or atomic replicas) — unchanged
    if (usePart) {
        float* pp = part + (long)blk * PART_STRIDE;
        #pragma unroll
        for (int mi = 0; mi < 2; ++mi)
            #pragma unroll
            for (int ni = 0; ni < 2; ++ni)
                #pragma unroll
                for (int j = 0; j < 4; ++j)
                    pp[og * 1024 + (mi * 16 + q * 4 + j) * 32 + ni * 16 + l15] = cc[mi][ni][j];
        if (l15 == 0) {
            #pragma unroll
            for (int mi = 0; mi < 2; ++mi)
                #pragma unroll
                for (int j = 0; j < 4; ++j)
                    pp[4096 + og * 32 + mi * 16 + q * 4 + j] = rsa[mi][j];
        }
    } else {
        float* pp = part + (long)(b * R + (blk % R)) * PART_STRIDE;
        #pragma unroll
        for (int mi = 0; mi < 2; ++mi)
            #pragma unroll
            for (int ni = 0; ni < 2; ++ni)
                #pragma unroll
                for (int j = 0; j < 4; ++j)
                    atomicAdd(&pp[og * 1024 + (mi * 16 + q * 4 + j) * 32 + ni * 16 + l15], cc[mi][ni][j]);
        if (l15 == 0) {
            #pragma unroll
            for (int mi = 0; mi < 2; ++mi)
                #pragma unroll
                for (int j = 0; j < 4; ++j)
                    atomicAdd(&pp[4096 + og * 32 + mi * 16 + q * 4 + j], rsa[mi][j]);
        }
    }
}

// ---------------- K1b: reduce partials -> ctx, rsum (atomic, sliced) -----
__global__ __launch_bounds__(128)
void k1b_reduce(float* __restrict__ ws, int PB) {
    const int S = 8;
    const int chunk = blockIdx.x % 33;
    const int rem   = blockIdx.x / 33;
    const int b     = rem & 1;
    const int slice = rem >> 1;
    const int j = chunk * 128 + threadIdx.x;       // [0, 4224)
    const int PBh = PB >> 1;
    const float* part = ws + WS_PART;
    float s = 0.f;
    for (int pi = b * PBh + slice; pi < (b + 1) * PBh; pi += S)
        s += part[(long)pi * PART_STRIDE + j];
    float* dst = (j < 4096) ? (ws + WS_CTX + b * 4096 + j)
                            : (ws + WS_RS + b * 128 + (j - 4096));
    atomicAdd(dst, s);
}

// ---------------- K2: ATb[up][o] = packed bf16 pair of A^T ---------------
__global__ __launch_bounds__(256)
void k2_prepA(const float* __restrict__ wout, float* __restrict__ ws) {
    __shared__ float wo[64 * 129];
    __shared__ float ct[4096];
    __shared__ float rsum[128];
    const int b   = blockIdx.x;
    const int tid = threadIdx.x;
    for (int i = tid; i < 8192; i += 256) wo[(i >> 7) * 129 + (i & 127)] = wout[i];
    for (int i = tid; i < 4096; i += 256) ct[i] = ws[WS_CTX + b * 4096 + i];
    if (tid < 128) rsum[tid] = ws[WS_RS + b * 128 + tid];
    __syncthreads();
    u32* atb = (u32*)ws + WS_ATB + b * 4096;
    const int o  = tid & 63;
    const int ug = tid >> 6;
    for (int i = 0; i < 16; ++i) {
        const int up = ug * 16 + i;
        const int hc0 = 2 * up, hc1 = 2 * up + 1;
        const int hh = hc0 >> 5;
        const int c0 = hc0 & 31, c1 = hc1 & 31;
        float s0 = 0.f, s1 = 0.f;
        #pragma unroll
        for (int d = 0; d < 32; ++d) {
            const float w = wo[o * 129 + hh * 32 + d];
            s0 = fmaf(w, ct[hh * 1024 + c0 * 32 + d], s0);
            s1 = fmaf(w, ct[hh * 1024 + c1 * 32 + d], s1);
        }
        atb[up * 64 + o] = pk2(s0 / rsum[hc0], s1 / rsum[hc1]);
    }
}

// ---------------- K3: q GEMM (MFMA) + in-reg softmax + A@q (MFMA) --------
// R10 kernel verbatim.
__global__ __launch_bounds__(256, 2)
void k3_out(const float* __restrict__ x, const float* __restrict__ wq,
            const float* __restrict__ bout, const float* __restrict__ wsf,
            float* __restrict__ out) {
    __shared__ u32 xbh[64 * 32];       // 8 KB
    __shared__ u32 xbl[64 * 32];       // 8 KB
    __shared__ u16 qb[64 * 128];       // [px][hc] bf16, swizzled, 16 KB
    const int blk  = blockIdx.x;
    const int b    = blk / NTILES;
    const int tile = blk % NTILES;
    const long i0  = (long)tile * 64;
    const int p    = threadIdx.x & 63;
    const int og   = __builtin_amdgcn_readfirstlane(threadIdx.x >> 6);
    const int q    = p >> 4;
    const int l15  = p & 15;
    const int yv   = (p & 7) << 2;
    const float* xg = x + (long)b * 64 * NPIX;

    // x loads first (coalesced, longest latency)
    float xl[16];
    {
        const float* xr = xg + (long)(og * 16) * NPIX + i0 + p;
        #pragma unroll
        for (int i = 0; i < 16; ++i) xl[i] = xr[(long)i * NPIX];
    }

    // W frags: q rows og*32..+32, split
    FragU wh[2][2], wl[2][2];
    #pragma unroll
    for (int mi = 0; mi < 2; ++mi)
        #pragma unroll
        for (int ks = 0; ks < 2; ++ks) {
            const int row = og * 32 + mi * 16 + l15;
            const float* wp = wq + row * 64 + ks * 32 + q * 4;
            float4 f0 = *(const float4*)wp;
            float4 f1 = *(const float4*)(wp + 16);
            split2(f0.x, f0.y, wh[mi][ks].u[0], wl[mi][ks].u[0]);
            split2(f0.z, f0.w, wh[mi][ks].u[1], wl[mi][ks].u[1]);
            split2(f1.x, f1.y, wh[mi][ks].u[2], wl[mi][ks].u[2]);
            split2(f1.z, f1.w, wh[mi][ks].u[3], wl[mi][ks].u[3]);
        }

    // ATb frags (per-b matrix, packed bf16 pairs)
    const u32* atb = (const u32*)wsf + WS_ATB + b * 4096;
    FragU af[4];
    #pragma unroll
    for (int ks = 0; ks < 4; ++ks) {
        const int up0 = ks * 16 + 2 * q;
        const int o   = og * 16 + l15;
        af[ks].u[0] = atb[(up0)     * 64 + o];
        af[ks].u[1] = atb[(up0 + 1) * 64 + o];
        af[ks].u[2] = atb[(up0 + 8) * 64 + o];
        af[ks].u[3] = atb[(up0 + 9) * 64 + o];
    }
    const float4 bias = *(const float4*)&bout[og * 16 + q * 4];

    // transpose-pack xl -> split bf16
    {
        u32 hb_[8], lb_[8];
        #pragma unroll
        for (int w = 0; w < 8; ++w) split2(xl[2 * w], xl[2 * w + 1], hb_[w], lb_[w]);
        const int yy = (p & 7) << 2;
        const int sA = (og * 8) ^ yy;
        const int sB = (og * 8 + 4) ^ yy;
        *(uint4*)&xbh[p * 32 + sA] = make_uint4(hb_[0], hb_[1], hb_[2], hb_[3]);
        *(uint4*)&xbh[p * 32 + sB] = make_uint4(hb_[4], hb_[5], hb_[6], hb_[7]);
        *(uint4*)&xbl[p * 32 + sA] = make_uint4(lb_[0], lb_[1], lb_[2], lb_[3]);
        *(uint4*)&xbl[p * 32 + sB] = make_uint4(lb_[4], lb_[5], lb_[6], lb_[7]);
    }
    __syncthreads();

    // phase 1 + softmax, per px-block ni
    #pragma unroll
    for (int ni = 0; ni < 4; ++ni) {
        const int rb = (ni * 16 + l15) * 32;
        FragU bh[2], bl[2];
        #pragma unroll
        for (int ks = 0; ks < 2; ++ks) {
            const int c0 = (ks * 16 + 2 * q) ^ yv;
            const int c1 = (ks * 16 + 2 * q + 8) ^ yv;
            uint2 t0 = *(const uint2*)&xbh[rb + c0];
            uint2 t1 = *(const uint2*)&xbh[rb + c1];
            bh[ks].u[0] = t0.x; bh[ks].u[1] = t0.y;
            bh[ks].u[2] = t1.x; bh[ks].u[3] = t1.y;
            uint2 s0 = *(const uint2*)&xbl[rb + c0];
            uint2 s1 = *(const uint2*)&xbl[rb + c1];
            bl[ks].u[0] = s0.x; bl[ks].u[1] = s0.y;
            bl[ks].u[2] = s1.x; bl[ks].u[3] = s1.y;
        }
        f32x4 a0 = (f32x4)0.f, a1 = (f32x4)0.f;
        #pragma unroll
        for (int ks = 0; ks < 2; ++ks) {
            a0 = MFMA(wh[0][ks].v, bh[ks].v, a0);
            a0 = MFMA(wh[0][ks].v, bl[ks].v, a0);
            a0 = MFMA(wl[0][ks].v, bh[ks].v, a0);
            a1 = MFMA(wh[1][ks].v, bh[ks].v, a1);
            a1 = MFMA(wh[1][ks].v, bl[ks].v, a1);
            a1 = MFMA(wl[1][ks].v, bh[ks].v, a1);
        }
        // softmax over head og's 32 rows for this lane's px column
        float mx = a0[0];
        #pragma unroll
        for (int j = 1; j < 4; ++j) mx = fmaxf(mx, a0[j]);
        #pragma unroll
        for (int j = 0; j < 4; ++j) mx = fmaxf(mx, a1[j]);
        mx = fmaxf(mx, __shfl_xor(mx, 16));
        mx = fmaxf(mx, __shfl_xor(mx, 32));
        float e0[4], e1[4], sm = 0.f;
        #pragma unroll
        for (int j = 0; j < 4; ++j) { e0[j] = __expf(a0[j] - mx); sm += e0[j]; }
        #pragma unroll
        for (int j = 0; j < 4; ++j) { e1[j] = __expf(a1[j] - mx); sm += e1[j]; }
        sm += __shfl_xor(sm, 16);
        sm += __shfl_xor(sm, 32);
        const float inv = 1.0f / sm;
        const int px = ni * 16 + l15;
        const int Xq = (px & 7) << 3;              // u16-unit swizzle (as before)
        u32* qbw = (u32*)qb;
        const int b0 = (px * 128 + ((og * 32 + q * 4) ^ Xq)) >> 1;
        const int b1 = (px * 128 + ((og * 32 + 16 + q * 4) ^ Xq)) >> 1;
        *(uint2*)&qbw[b0] = make_uint2(pk2(e0[0] * inv, e0[1] * inv),
                                       pk2(e0[2] * inv, e0[3] * inv));
        *(uint2*)&qbw[b1] = make_uint2(pk2(e1[0] * inv, e1[1] * inv),
                                       pk2(e1[2] * inv, e1[3] * inv));
    }
    __syncthreads();

    // phase 3: out = A^T qsm + bias
    const u32* qb32 = (const u32*)qb;
    #pragma unroll
    for (int ni = 0; ni < 4; ++ni) {
        const int px = ni * 16 + l15;
        const int rb = px * 64;
        f32x4 a3 = (f32x4)0.f;
        #pragma unroll
        for (int ks = 0; ks < 4; ++ks) {
            const int c0 = (ks * 16 + 2 * q) ^ yv;
            const int c1 = (ks * 16 + 2 * q + 8) ^ yv;
            uint2 t0 = *(const uint2*)&qb32[rb + c0];
            uint2 t1 = *(const uint2*)&qb32[rb + c1];
            FragU bq;
            bq.u[0] = t0.x; bq.u[1] = t0.y; bq.u[2] = t1.x; bq.u[3] = t1.y;
            a3 = MFMA(af[ks].v, bq.v, a3);
        }
        #pragma unroll
        for (int j = 0; j < 4; ++j)
            out[((long)b * 64 + og * 16 + q * 4 + j) * NPIX + i0 + px] = a3[j] + bias[j];
    }
}

extern "C" void kernel_launch(void* const* d_in, const int* in_sizes, int n_in,
                              void* d_out, int out_size, void* d_ws, size_t ws_size,
                              hipStream_t stream) {
    (void)in_sizes; (void)n_in; (void)out_size;
    const float* x     = (const float*)d_in[0];
    const float* w_qkv = (const float*)d_in[1];
    const float* w_out = (const float*)d_in[2];
    const float* b_out = (const float*)d_in[3];
    float* out = (float*)d_out;
    float* ws  = (float*)d_ws;

    const size_t need_part = ((size_t)WS_PART + (size_t)K1_BLOCKS * PART_STRIDE) * 4;
    const int usePart = (ws_size >= need_part) ? 1 : 0;
    int R = 8;
    const size_t need_r8 = ((size_t)WS_PART + (size_t)2 * 8 * PART_STRIDE) * 4;
    if (!usePart && ws_size < need_r8) R = 1;
    const int PB = usePart ? K1_BLOCKS : 2 * R;
    float* part = ws + WS_PART;

    if (!usePart)
        hipMemsetAsync(part, 0, (size_t)PB * PART_STRIDE * 4, stream);
    hipLaunchKernelGGL(k1_ctx, dim3(K1_BLOCKS), dim3(256), 0, stream,
                       x, w_qkv, part, usePart, R);
    hipMemsetAsync(ws + WS_CTX, 0, (size_t)(2 * PART_STRIDE) * 4, stream);
    hipLaunchKernelGGL(k1b_reduce, dim3(528), dim3(128), 0, stream, ws, PB);
    hipLaunchKernelGGL(k2_prepA, dim3(2), dim3(256), 0, stream, w_out, ws);
    hipLaunchKernelGGL(k3_out, dim3(2 * NTILES), dim3(256), 0, stream,
                       x, w_qkv, b_out, ws, out);
}

// Round 12
// 95.844 us; speedup vs baseline: 1.1121x; 1.0499x over previous
//
#include <hip/hip_runtime.h>

typedef unsigned int u32;
typedef unsigned short u16;
typedef __attribute__((ext_vector_type(8))) short bf16x8;   // 8 bf16 in 4 VGPRs
typedef __attribute__((ext_vector_type(4))) float f32x4;

#define NPIX 110592            // 48^3
#define NTILES 1728            // NPIX/64 per batch
#define K1_BLOCKS 864          // each block: one 256-px group (4 tiles), b-aligned
#define K1_TPB 4
#define PART_STRIDE 4224       // 4096 ctx + 128 rowsum

// ws layout (4-byte slots)
#define WS_CTX   0             // 2*4096 f32
#define WS_RS    8192          // 2*128 f32
#define WS_ATB   8448          // 2*4096 u32 (packed bf16 pairs of A^T)
#define WS_PART  16640

union FragU { u32 u[4]; bf16x8 v; };

#define MFMA(a,b,c) __builtin_amdgcn_mfma_f32_16x16x32_bf16((a),(b),(c),0,0,0)

__device__ __forceinline__ u32 f2bf(float f) {            // RNE f32->bf16 bits
    u32 u = __float_as_uint(f);
    return (u + 0x7FFFu + ((u >> 16) & 1u)) >> 16;
}
__device__ __forceinline__ float bf2f(u32 bits) { return __uint_as_float(bits << 16); }
__device__ __forceinline__ u32 pk2(float a, float b) { return f2bf(a) | (f2bf(b) << 16); }
__device__ __forceinline__ void split2(float a, float b, u32& hi, u32& lo) {
    u32 ha = f2bf(a), hb = f2bf(b);
    hi = ha | (hb << 16);
    lo = pk2(a - bf2f(ha), b - bf2f(hb));
}

// ---------------- K1: k,v GEMM (MFMA) + ctx/rowsum (MFMA) ----------------
// R12: kvb DELETED. Phase-1 acc D[px][o] (lane: o=l15, px=ni*16+4q+j) is
// directly the A-frag (ek: c=l15) and B-frag (v: d=l15) layout that ctx's
// MFMA needs for k=px: element e <-> px = ksp*32 + (e&3)+4q+16*(e>>2),
// i.e. u[0..1] from ni=2ksp, u[2..3] from ni=2ksp+1. Per-ksp slicing keeps
// acc[4][2] (32 VGPR) live. Same exp->bf16 rounding => bit-identical output.
// LDS = xbh only (32 KB); no barriers in the tile loop.
__global__ __launch_bounds__(256, 3)
void k1_ctx(const float* __restrict__ x, const float* __restrict__ wq,
            float* __restrict__ part, int usePart, int R) {
    __shared__ u32 xbh[256 * 32];      // [px][cpair hi], swizzled, 32 KB
    const int blk = blockIdx.x;
    const int p   = threadIdx.x & 63;
    const int og  = __builtin_amdgcn_readfirstlane(threadIdx.x >> 6);
    const int b   = blk / (K1_BLOCKS / 2);
    const int q   = p >> 4;
    const int l15 = p & 15;
    const int yv  = (p & 7) << 2;
    const float* xg = x + (long)b * 64 * NPIX;

    // W frags: mi 0,1 -> K rows og*32+mi*16; mi 2,3 -> V rows 128+og*32+..
    FragU wh[4][2], wl[4][2];
    #pragma unroll
    for (int mi = 0; mi < 4; ++mi)
        #pragma unroll
        for (int ks = 0; ks < 2; ++ks) {
            const int kvrow = (mi < 2) ? (og * 32 + mi * 16) : (128 + og * 32 + (mi - 2) * 16);
            const int row = 128 + kvrow + l15;
            const float* wp = wq + row * 64 + ks * 32 + q * 4;
            float4 f0 = *(const float4*)wp;
            float4 f1 = *(const float4*)(wp + 16);
            split2(f0.x, f0.y, wh[mi][ks].u[0], wl[mi][ks].u[0]);
            split2(f0.z, f0.w, wh[mi][ks].u[1], wl[mi][ks].u[1]);
            split2(f1.x, f1.y, wh[mi][ks].u[2], wl[mi][ks].u[2]);
            split2(f1.z, f1.w, wh[mi][ks].u[3], wl[mi][ks].u[3]);
        }

    FragU ones;
    #pragma unroll
    for (int i = 0; i < 4; ++i) ones.u[i] = 0x3F803F80u;

    f32x4 cc[2][2], rsa[2];
    #pragma unroll
    for (int mi = 0; mi < 2; ++mi) {
        #pragma unroll
        for (int ni = 0; ni < 2; ++ni) cc[mi][ni] = (f32x4)0.f;
        rsa[mi] = (f32x4)0.f;
    }

    // ---- stage group's x: 16 rows/wave x 256 px, 1KB/instr, bf16-hi pack
    const long i0g = (long)(blk * K1_TPB - b * NTILES) * 64;   // group px start
    #pragma unroll
    for (int ch = 0; ch < 2; ++ch) {
        f32x4 xl4[8];
        const float* xr = xg + (long)(og * 16 + ch * 8) * NPIX + i0g + 4 * p;
        #pragma unroll
        for (int i = 0; i < 8; ++i) xl4[i] = *(const f32x4*)(xr + (long)i * NPIX);
        #pragma unroll
        for (int j = 0; j < 4; ++j) {
            const int px = 4 * p + j;
            const int yy = (px & 7) << 2;
            u32 h[4];
            #pragma unroll
            for (int w = 0; w < 4; ++w) h[w] = pk2(xl4[2 * w][j], xl4[2 * w + 1][j]);
            const int sA = (og * 8 + ch * 4) ^ yy;
            *(uint4*)&xbh[px * 32 + sA] = make_uint4(h[0], h[1], h[2], h[3]);
        }
    }
    __syncthreads();               // xbh ready for all 4 tiles (read-only after)

    #pragma unroll 1
    for (int tt = 0; tt < K1_TPB; ++tt) {
        #pragma unroll
        for (int ksp = 0; ksp < 2; ++ksp) {
            // phase 1 for this ksp's two 16-px blocks: acc[mi][ni2]
            f32x4 acc[4][2];
            #pragma unroll
            for (int ni2 = 0; ni2 < 2; ++ni2) {
                const int ni = ksp * 2 + ni2;
                const int rb = (tt * 64 + ni * 16 + l15) * 32;
                FragU bh[2];
                #pragma unroll
                for (int ks = 0; ks < 2; ++ks) {
                    const int c0 = (ks * 16 + 2 * q) ^ yv;
                    const int c1 = (ks * 16 + 2 * q + 8) ^ yv;
                    uint2 t0 = *(const uint2*)&xbh[rb + c0];
                    uint2 t1 = *(const uint2*)&xbh[rb + c1];
                    bh[ks].u[0] = t0.x; bh[ks].u[1] = t0.y;
                    bh[ks].u[2] = t1.x; bh[ks].u[3] = t1.y;
                }
                #pragma unroll
                for (int mi = 0; mi < 4; ++mi) {
                    f32x4 a = (f32x4)0.f;
                    #pragma unroll
                    for (int ks = 0; ks < 2; ++ks) {
                        a = MFMA(bh[ks].v, wh[mi][ks].v, a);
                        a = MFMA(bh[ks].v, wl[mi][ks].v, a);
                    }
                    acc[mi][ni2] = a;
                }
            }
            // convert acc -> ek (exp, mi 0,1) / v (mi 2,3) bf16 fragments
            FragU ak[2], av[2];
            #pragma unroll
            for (int m2 = 0; m2 < 2; ++m2) {
                float e0[4], e1[4];
                #pragma unroll
                for (int j = 0; j < 4; ++j) {
                    e0[j] = __expf(acc[m2][0][j]);
                    e1[j] = __expf(acc[m2][1][j]);
                }
                ak[m2].u[0] = pk2(e0[0], e0[1]);
                ak[m2].u[1] = pk2(e0[2], e0[3]);
                ak[m2].u[2] = pk2(e1[0], e1[1]);
                ak[m2].u[3] = pk2(e1[2], e1[3]);
                av[m2].u[0] = pk2(acc[2 + m2][0][0], acc[2 + m2][0][1]);
                av[m2].u[1] = pk2(acc[2 + m2][0][2], acc[2 + m2][0][3]);
                av[m2].u[2] = pk2(acc[2 + m2][1][0], acc[2 + m2][1][1]);
                av[m2].u[3] = pk2(acc[2 + m2][1][2], acc[2 + m2][1][3]);
            }
            // phase 2: ctx += EK x V^T over this ksp's 32 px; rowsum B=ones
            #pragma unroll
            for (int mi = 0; mi < 2; ++mi) {
                #pragma unroll
                for (int nj = 0; nj < 2; ++nj)
                    cc[mi][nj] = MFMA(ak[mi].v, av[nj].v, cc[mi][nj]);
                rsa[mi] = MFMA(ak[mi].v, ones.v, rsa[mi]);
            }
        }
    }

    // epilogue: per-block partials (or atomic replicas) — unchanged
    if (usePart) {
        float* pp = part + (long)blk * PART_STRIDE;
        #pragma unroll
        for (int mi = 0; mi < 2; ++mi)
            #pragma unroll
            for (int ni = 0; ni < 2; ++ni)
                #pragma unroll
                for (int j = 0; j < 4; ++j)
                    pp[og * 1024 + (mi * 16 + q * 4 + j) * 32 + ni * 16 + l15] = cc[mi][ni][j];
        if (l15 == 0) {
            #pragma unroll
            for (int mi = 0; mi < 2; ++mi)
                #pragma unroll
                for (int j = 0; j < 4; ++j)
                    pp[4096 + og * 32 + mi * 16 + q * 4 + j] = rsa[mi][j];
        }
    } else {
        float* pp = part + (long)(b * R + (blk % R)) * PART_STRIDE;
        #pragma unroll
        for (int mi = 0; mi < 2; ++mi)
            #pragma unroll
            for (int ni = 0; ni < 2; ++ni)
                #pragma unroll
                for (int j = 0; j < 4; ++j)
                    atomicAdd(&pp[og * 1024 + (mi * 16 + q * 4 + j) * 32 + ni * 16 + l15], cc[mi][ni][j]);
        if (l15 == 0) {
            #pragma unroll
            for (int mi = 0; mi < 2; ++mi)
                #pragma unroll
                for (int j = 0; j < 4; ++j)
                    atomicAdd(&pp[4096 + og * 32 + mi * 16 + q * 4 + j], rsa[mi][j]);
        }
    }
}

// ---------------- K1b: reduce partials -> ctx, rsum (atomic, sliced) -----
__global__ __launch_bounds__(128)
void k1b_reduce(float* __restrict__ ws, int PB) {
    const int S = 8;
    const int chunk = blockIdx.x % 33;
    const int rem   = blockIdx.x / 33;
    const int b     = rem & 1;
    const int slice = rem >> 1;
    const int j = chunk * 128 + threadIdx.x;       // [0, 4224)
    const int PBh = PB >> 1;
    const float* part = ws + WS_PART;
    float s = 0.f;
    for (int pi = b * PBh + slice; pi < (b + 1) * PBh; pi += S)
        s += part[(long)pi * PART_STRIDE + j];
    float* dst = (j < 4096) ? (ws + WS_CTX + b * 4096 + j)
                            : (ws + WS_RS + b * 128 + (j - 4096));
    atomicAdd(dst, s);
}

// ---------------- K2: ATb[up][o] = packed bf16 pair of A^T ---------------
__global__ __launch_bounds__(256)
void k2_prepA(const float* __restrict__ wout, float* __restrict__ ws) {
    __shared__ float wo[64 * 129];
    __shared__ float ct[4096];
    __shared__ float rsum[128];
    const int b   = blockIdx.x;
    const int tid = threadIdx.x;
    for (int i = tid; i < 8192; i += 256) wo[(i >> 7) * 129 + (i & 127)] = wout[i];
    for (int i = tid; i < 4096; i += 256) ct[i] = ws[WS_CTX + b * 4096 + i];
    if (tid < 128) rsum[tid] = ws[WS_RS + b * 128 + tid];
    __syncthreads();
    u32* atb = (u32*)ws + WS_ATB + b * 4096;
    const int o  = tid & 63;
    const int ug = tid >> 6;
    for (int i = 0; i < 16; ++i) {
        const int up = ug * 16 + i;
        const int hc0 = 2 * up, hc1 = 2 * up + 1;
        const int hh = hc0 >> 5;
        const int c0 = hc0 & 31, c1 = hc1 & 31;
        float s0 = 0.f, s1 = 0.f;
        #pragma unroll
        for (int d = 0; d < 32; ++d) {
            const float w = wo[o * 129 + hh * 32 + d];
            s0 = fmaf(w, ct[hh * 1024 + c0 * 32 + d], s0);
            s1 = fmaf(w, ct[hh * 1024 + c1 * 32 + d], s1);
        }
        atb[up * 64 + o] = pk2(s0 / rsum[hc0], s1 / rsum[hc1]);
    }
}

// ---------------- K3: q GEMM (MFMA) + in-reg softmax + A@q (MFMA) --------
// R10 kernel verbatim.
__global__ __launch_bounds__(256, 2)
void k3_out(const float* __restrict__ x, const float* __restrict__ wq,
            const float* __restrict__ bout, const float* __restrict__ wsf,
            float* __restrict__ out) {
    __shared__ u32 xbh[64 * 32];       // 8 KB
    __shared__ u32 xbl[64 * 32];       // 8 KB
    __shared__ u16 qb[64 * 128];       // [px][hc] bf16, swizzled, 16 KB
    const int blk  = blockIdx.x;
    const int b    = blk / NTILES;
    const int tile = blk % NTILES;
    const long i0  = (long)tile * 64;
    const int p    = threadIdx.x & 63;
    const int og   = __builtin_amdgcn_readfirstlane(threadIdx.x >> 6);
    const int q    = p >> 4;
    const int l15  = p & 15;
    const int yv   = (p & 7) << 2;
    const float* xg = x + (long)b * 64 * NPIX;

    // x loads first (coalesced, longest latency)
    float xl[16];
    {
        const float* xr = xg + (long)(og * 16) * NPIX + i0 + p;
        #pragma unroll
        for (int i = 0; i < 16; ++i) xl[i] = xr[(long)i * NPIX];
    }

    // W frags: q rows og*32..+32, split
    FragU wh[2][2], wl[2][2];
    #pragma unroll
    for (int mi = 0; mi < 2; ++mi)
        #pragma unroll
        for (int ks = 0; ks < 2; ++ks) {
            const int row = og * 32 + mi * 16 + l15;
            const float* wp = wq + row * 64 + ks * 32 + q * 4;
            float4 f0 = *(const float4*)wp;
            float4 f1 = *(const float4*)(wp + 16);
            split2(f0.x, f0.y, wh[mi][ks].u[0], wl[mi][ks].u[0]);
            split2(f0.z, f0.w, wh[mi][ks].u[1], wl[mi][ks].u[1]);
            split2(f1.x, f1.y, wh[mi][ks].u[2], wl[mi][ks].u[2]);
            split2(f1.z, f1.w, wh[mi][ks].u[3], wl[mi][ks].u[3]);
        }

    // ATb frags (per-b matrix, packed bf16 pairs)
    const u32* atb = (const u32*)wsf + WS_ATB + b * 4096;
    FragU af[4];
    #pragma unroll
    for (int ks = 0; ks < 4; ++ks) {
        const int up0 = ks * 16 + 2 * q;
        const int o   = og * 16 + l15;
        af[ks].u[0] = atb[(up0)     * 64 + o];
        af[ks].u[1] = atb[(up0 + 1) * 64 + o];
        af[ks].u[2] = atb[(up0 + 8) * 64 + o];
        af[ks].u[3] = atb[(up0 + 9) * 64 + o];
    }
    const float4 bias = *(const float4*)&bout[og * 16 + q * 4];

    // transpose-pack xl -> split bf16
    {
        u32 hb_[8], lb_[8];
        #pragma unroll
        for (int w = 0; w < 8; ++w) split2(xl[2 * w], xl[2 * w + 1], hb_[w], lb_[w]);
        const int yy = (p & 7) << 2;
        const int sA = (og * 8) ^ yy;
        const int sB = (og * 8 + 4) ^ yy;
        *(uint4*)&xbh[p * 32 + sA] = make_uint4(hb_[0], hb_[1], hb_[2], hb_[3]);
        *(uint4*)&xbh[p * 32 + sB] = make_uint4(hb_[4], hb_[5], hb_[6], hb_[7]);
        *(uint4*)&xbl[p * 32 + sA] = make_uint4(lb_[0], lb_[1], lb_[2], lb_[3]);
        *(uint4*)&xbl[p * 32 + sB] = make_uint4(lb_[4], lb_[5], lb_[6], lb_[7]);
    }
    __syncthreads();

    // phase 1 + softmax, per px-block ni
    #pragma unroll
    for (int ni = 0; ni < 4; ++ni) {
        const int rb = (ni * 16 + l15) * 32;
        FragU bh[2], bl[2];
        #pragma unroll
        for (int ks = 0; ks < 2; ++ks) {
            const int c0 = (ks * 16 + 2 * q) ^ yv;
            const int c1 = (ks * 16 + 2 * q + 8) ^ yv;
            uint2 t0 = *(const uint2*)&xbh[rb + c0];
            uint2 t1 = *(const uint2*)&xbh[rb + c1];
            bh[ks].u[0] = t0.x; bh[ks].u[1] = t0.y;
            bh[ks].u[2] = t1.x; bh[ks].u[3] = t1.y;
            uint2 s0 = *(const uint2*)&xbl[rb + c0];
            uint2 s1 = *(const uint2*)&xbl[rb + c1];
            bl[ks].u[0] = s0.x; bl[ks].u[1] = s0.y;
            bl[ks].u[2] = s1.x; bl[ks].u[3] = s1.y;
        }
        f32x4 a0 = (f32x4)0.f, a1 = (f32x4)0.f;
        #pragma unroll
        for (int ks = 0; ks < 2; ++ks) {
            a0 = MFMA(wh[0][ks].v, bh[ks].v, a0);
            a0 = MFMA(wh[0][ks].v, bl[ks].v, a0);
            a0 = MFMA(wl[0][ks].v, bh[ks].v, a0);
            a1 = MFMA(wh[1][ks].v, bh[ks].v, a1);
            a1 = MFMA(wh[1][ks].v, bl[ks].v, a1);
            a1 = MFMA(wl[1][ks].v, bh[ks].v, a1);
        }
        // softmax over head og's 32 rows for this lane's px column
        float mx = a0[0];
        #pragma unroll
        for (int j = 1; j < 4; ++j) mx = fmaxf(mx, a0[j]);
        #pragma unroll
        for (int j = 0; j < 4; ++j) mx = fmaxf(mx, a1[j]);
        mx = fmaxf(mx, __shfl_xor(mx, 16));
        mx = fmaxf(mx, __shfl_xor(mx, 32));
        float e0[4], e1[4], sm = 0.f;
        #pragma unroll
        for (int j = 0; j < 4; ++j) { e0[j] = __expf(a0[j] - mx); sm += e0[j]; }
        #pragma unroll
        for (int j = 0; j < 4; ++j) { e1[j] = __expf(a1[j] - mx); sm += e1[j]; }
        sm += __shfl_xor(sm, 16);
        sm += __shfl_xor(sm, 32);
        const float inv = 1.0f / sm;
        const int px = ni * 16 + l15;
        const int Xq = (px & 7) << 3;              // u16-unit swizzle (as before)
        u32* qbw = (u32*)qb;
        const int b0 = (px * 128 + ((og * 32 + q * 4) ^ Xq)) >> 1;
        const int b1 = (px * 128 + ((og * 32 + 16 + q * 4) ^ Xq)) >> 1;
        *(uint2*)&qbw[b0] = make_uint2(pk2(e0[0] * inv, e0[1] * inv),
                                       pk2(e0[2] * inv, e0[3] * inv));
        *(uint2*)&qbw[b1] = make_uint2(pk2(e1[0] * inv, e1[1] * inv),
                                       pk2(e1[2] * inv, e1[3] * inv));
    }
    __syncthreads();

    // phase 3: out = A^T qsm + bias
    const u32* qb32 = (const u32*)qb;
    #pragma unroll
    for (int ni = 0; ni < 4; ++ni) {
        const int px = ni * 16 + l15;
        const int rb = px * 64;
        f32x4 a3 = (f32x4)0.f;
        #pragma unroll
        for (int ks = 0; ks < 4; ++ks) {
            const int c0 = (ks * 16 + 2 * q) ^ yv;
            const int c1 = (ks * 16 + 2 * q + 8) ^ yv;
            uint2 t0 = *(const uint2*)&qb32[rb + c0];
            uint2 t1 = *(const uint2*)&qb32[rb + c1];
            FragU bq;
            bq.u[0] = t0.x; bq.u[1] = t0.y; bq.u[2] = t1.x; bq.u[3] = t1.y;
            a3 = MFMA(af[ks].v, bq.v, a3);
        }
        #pragma unroll
        for (int j = 0; j < 4; ++j)
            out[((long)b * 64 + og * 16 + q * 4 + j) * NPIX + i0 + px] = a3[j] + bias[j];
    }
}

extern "C" void kernel_launch(void* const* d_in, const int* in_sizes, int n_in,
                              void* d_out, int out_size, void* d_ws, size_t ws_size,
                              hipStream_t stream) {
    (void)in_sizes; (void)n_in; (void)out_size;
    const float* x     = (const float*)d_in[0];
    const float* w_qkv = (const float*)d_in[1];
    const float* w_out = (const float*)d_in[2];
    const float* b_out = (const float*)d_in[3];
    float* out = (float*)d_out;
    float* ws  = (float*)d_ws;

    const size_t need_part = ((size_t)WS_PART + (size_t)K1_BLOCKS * PART_STRIDE) * 4;
    const int usePart = (ws_size >= need_part) ? 1 : 0;
    int R = 8;
    const size_t need_r8 = ((size_t)WS_PART + (size_t)2 * 8 * PART_STRIDE) * 4;
    if (!usePart && ws_size < need_r8) R = 1;
    const int PB = usePart ? K1_BLOCKS : 2 * R;
    float* part = ws + WS_PART;

    if (!usePart)
        hipMemsetAsync(part, 0, (size_t)PB * PART_STRIDE * 4, stream);
    hipLaunchKernelGGL(k1_ctx, dim3(K1_BLOCKS), dim3(256), 0, stream,
                       x, w_qkv, part, usePart, R);
    hipMemsetAsync(ws + WS_CTX, 0, (size_t)(2 * PART_STRIDE) * 4, stream);
    hipLaunchKernelGGL(k1b_reduce, dim3(528), dim3(128), 0, stream, ws, PB);
    hipLaunchKernelGGL(k2_prepA, dim3(2), dim3(256), 0, stream, w_out, ws);
    hipLaunchKernelGGL(k3_out, dim3(2 * NTILES), dim3(256), 0, stream,
                       x, w_qkv, b_out, ws, out);
}

// Round 13
// 94.195 us; speedup vs baseline: 1.1315x; 1.0175x over previous
//
#include <hip/hip_runtime.h>

typedef unsigned int u32;
typedef unsigned short u16;
typedef __attribute__((ext_vector_type(8))) short bf16x8;   // 8 bf16 in 4 VGPRs
typedef __attribute__((ext_vector_type(4))) float f32x4;

#define NPIX 110592            // 48^3
#define NTILES 1728            // NPIX/64 per batch
#define K1_BLOCKS 864          // each block: one 256-px group (4 tiles), b-aligned
#define K1_TPB 4
#define PART_STRIDE 4224       // 4096 ctx + 128 rowsum

// ws layout (4-byte slots)
#define WS_ATB   0             // 2*4096 u32 (packed bf16 pairs of A^T)
#define WS_P2    8192          // 16 slices x 4224 f32 (slice-partial ctx/rsum)
#define WS_PART  75776

union FragU { u32 u[4]; bf16x8 v; };

#define MFMA(a,b,c) __builtin_amdgcn_mfma_f32_16x16x32_bf16((a),(b),(c),0,0,0)

__device__ __forceinline__ u32 f2bf(float f) {            // RNE f32->bf16 bits
    u32 u = __float_as_uint(f);
    return (u + 0x7FFFu + ((u >> 16) & 1u)) >> 16;
}
__device__ __forceinline__ float bf2f(u32 bits) { return __uint_as_float(bits << 16); }
__device__ __forceinline__ u32 pk2(float a, float b) { return f2bf(a) | (f2bf(b) << 16); }
__device__ __forceinline__ void split2(float a, float b, u32& hi, u32& lo) {
    u32 ha = f2bf(a), hb = f2bf(b);
    hi = ha | (hb << 16);
    lo = pk2(a - bf2f(ha), b - bf2f(hb));
}

// ---------------- K1: k,v GEMM (MFMA) + ctx/rowsum (MFMA) ----------------
// R12 kernel verbatim (kvb-free, reg-direct phase1->phase2).
__global__ __launch_bounds__(256, 3)
void k1_ctx(const float* __restrict__ x, const float* __restrict__ wq,
            float* __restrict__ part, int usePart, int R) {
    __shared__ u32 xbh[256 * 32];      // [px][cpair hi], swizzled, 32 KB
    const int blk = blockIdx.x;
    const int p   = threadIdx.x & 63;
    const int og  = __builtin_amdgcn_readfirstlane(threadIdx.x >> 6);
    const int b   = blk / (K1_BLOCKS / 2);
    const int q   = p >> 4;
    const int l15 = p & 15;
    const int yv  = (p & 7) << 2;
    const float* xg = x + (long)b * 64 * NPIX;

    FragU wh[4][2], wl[4][2];
    #pragma unroll
    for (int mi = 0; mi < 4; ++mi)
        #pragma unroll
        for (int ks = 0; ks < 2; ++ks) {
            const int kvrow = (mi < 2) ? (og * 32 + mi * 16) : (128 + og * 32 + (mi - 2) * 16);
            const int row = 128 + kvrow + l15;
            const float* wp = wq + row * 64 + ks * 32 + q * 4;
            float4 f0 = *(const float4*)wp;
            float4 f1 = *(const float4*)(wp + 16);
            split2(f0.x, f0.y, wh[mi][ks].u[0], wl[mi][ks].u[0]);
            split2(f0.z, f0.w, wh[mi][ks].u[1], wl[mi][ks].u[1]);
            split2(f1.x, f1.y, wh[mi][ks].u[2], wl[mi][ks].u[2]);
            split2(f1.z, f1.w, wh[mi][ks].u[3], wl[mi][ks].u[3]);
        }

    FragU ones;
    #pragma unroll
    for (int i = 0; i < 4; ++i) ones.u[i] = 0x3F803F80u;

    f32x4 cc[2][2], rsa[2];
    #pragma unroll
    for (int mi = 0; mi < 2; ++mi) {
        #pragma unroll
        for (int ni = 0; ni < 2; ++ni) cc[mi][ni] = (f32x4)0.f;
        rsa[mi] = (f32x4)0.f;
    }

    const long i0g = (long)(blk * K1_TPB - b * NTILES) * 64;   // group px start
    #pragma unroll
    for (int ch = 0; ch < 2; ++ch) {
        f32x4 xl4[8];
        const float* xr = xg + (long)(og * 16 + ch * 8) * NPIX + i0g + 4 * p;
        #pragma unroll
        for (int i = 0; i < 8; ++i) xl4[i] = *(const f32x4*)(xr + (long)i * NPIX);
        #pragma unroll
        for (int j = 0; j < 4; ++j) {
            const int px = 4 * p + j;
            const int yy = (px & 7) << 2;
            u32 h[4];
            #pragma unroll
            for (int w = 0; w < 4; ++w) h[w] = pk2(xl4[2 * w][j], xl4[2 * w + 1][j]);
            const int sA = (og * 8 + ch * 4) ^ yy;
            *(uint4*)&xbh[px * 32 + sA] = make_uint4(h[0], h[1], h[2], h[3]);
        }
    }
    __syncthreads();               // xbh ready for all 4 tiles (read-only after)

    #pragma unroll 1
    for (int tt = 0; tt < K1_TPB; ++tt) {
        #pragma unroll
        for (int ksp = 0; ksp < 2; ++ksp) {
            f32x4 acc[4][2];
            #pragma unroll
            for (int ni2 = 0; ni2 < 2; ++ni2) {
                const int ni = ksp * 2 + ni2;
                const int rb = (tt * 64 + ni * 16 + l15) * 32;
                FragU bh[2];
                #pragma unroll
                for (int ks = 0; ks < 2; ++ks) {
                    const int c0 = (ks * 16 + 2 * q) ^ yv;
                    const int c1 = (ks * 16 + 2 * q + 8) ^ yv;
                    uint2 t0 = *(const uint2*)&xbh[rb + c0];
                    uint2 t1 = *(const uint2*)&xbh[rb + c1];
                    bh[ks].u[0] = t0.x; bh[ks].u[1] = t0.y;
                    bh[ks].u[2] = t1.x; bh[ks].u[3] = t1.y;
                }
                #pragma unroll
                for (int mi = 0; mi < 4; ++mi) {
                    f32x4 a = (f32x4)0.f;
                    #pragma unroll
                    for (int ks = 0; ks < 2; ++ks) {
                        a = MFMA(bh[ks].v, wh[mi][ks].v, a);
                        a = MFMA(bh[ks].v, wl[mi][ks].v, a);
                    }
                    acc[mi][ni2] = a;
                }
            }
            FragU ak[2], av[2];
            #pragma unroll
            for (int m2 = 0; m2 < 2; ++m2) {
                float e0[4], e1[4];
                #pragma unroll
                for (int j = 0; j < 4; ++j) {
                    e0[j] = __expf(acc[m2][0][j]);
                    e1[j] = __expf(acc[m2][1][j]);
                }
                ak[m2].u[0] = pk2(e0[0], e0[1]);
                ak[m2].u[1] = pk2(e0[2], e0[3]);
                ak[m2].u[2] = pk2(e1[0], e1[1]);
                ak[m2].u[3] = pk2(e1[2], e1[3]);
                av[m2].u[0] = pk2(acc[2 + m2][0][0], acc[2 + m2][0][1]);
                av[m2].u[1] = pk2(acc[2 + m2][0][2], acc[2 + m2][0][3]);
                av[m2].u[2] = pk2(acc[2 + m2][1][0], acc[2 + m2][1][1]);
                av[m2].u[3] = pk2(acc[2 + m2][1][2], acc[2 + m2][1][3]);
            }
            #pragma unroll
            for (int mi = 0; mi < 2; ++mi) {
                #pragma unroll
                for (int nj = 0; nj < 2; ++nj)
                    cc[mi][nj] = MFMA(ak[mi].v, av[nj].v, cc[mi][nj]);
                rsa[mi] = MFMA(ak[mi].v, ones.v, rsa[mi]);
            }
        }
    }

    if (usePart) {
        float* pp = part + (long)blk * PART_STRIDE;
        #pragma unroll
        for (int mi = 0; mi < 2; ++mi)
            #pragma unroll
            for (int ni = 0; ni < 2; ++ni)
                #pragma unroll
                for (int j = 0; j < 4; ++j)
                    pp[og * 1024 + (mi * 16 + q * 4 + j) * 32 + ni * 16 + l15] = cc[mi][ni][j];
        if (l15 == 0) {
            #pragma unroll
            for (int mi = 0; mi < 2; ++mi)
                #pragma unroll
                for (int j = 0; j < 4; ++j)
                    pp[4096 + og * 32 + mi * 16 + q * 4 + j] = rsa[mi][j];
        }
    } else {
        float* pp = part + (long)(b * R + (blk % R)) * PART_STRIDE;
        #pragma unroll
        for (int mi = 0; mi < 2; ++mi)
            #pragma unroll
            for (int ni = 0; ni < 2; ++ni)
                #pragma unroll
                for (int j = 0; j < 4; ++j)
                    atomicAdd(&pp[og * 1024 + (mi * 16 + q * 4 + j) * 32 + ni * 16 + l15], cc[mi][ni][j]);
        if (l15 == 0) {
            #pragma unroll
            for (int mi = 0; mi < 2; ++mi)
                #pragma unroll
                for (int j = 0; j < 4; ++j)
                    atomicAdd(&pp[4096 + og * 32 + mi * 16 + q * 4 + j], rsa[mi][j]);
        }
    }
}

// ---------------- K1b: reduce partials -> 16 slice-partials (no atomics) --
__global__ __launch_bounds__(128)
void k1b_reduce(float* __restrict__ ws, int PB) {
    const int S = 8;
    const int chunk = blockIdx.x % 33;
    const int rem   = blockIdx.x / 33;
    const int b     = rem & 1;
    const int slice = rem >> 1;
    const int j = chunk * 128 + threadIdx.x;       // [0, 4224)
    const int PBh = PB >> 1;
    const float* part = ws + WS_PART;
    float s = 0.f;
    for (int pi = b * PBh + slice; pi < (b + 1) * PBh; pi += S)
        s += part[(long)pi * PART_STRIDE + j];
    ws[WS_P2 + (long)(b * S + slice) * PART_STRIDE + j] = s;
}

// ---------------- K2: ATb[up][o]; sums the 8 slice-partials on load ------
__global__ __launch_bounds__(256)
void k2_prepA(const float* __restrict__ wout, float* __restrict__ ws) {
    __shared__ float wo[64 * 129];
    __shared__ float ct[4096];
    __shared__ float rsum[128];
    const int b   = blockIdx.x;
    const int tid = threadIdx.x;
    for (int i = tid; i < 8192; i += 256) wo[(i >> 7) * 129 + (i & 127)] = wout[i];
    for (int i = tid; i < 4096; i += 256) {
        float s = 0.f;
        #pragma unroll
        for (int s8 = 0; s8 < 8; ++s8)
            s += ws[WS_P2 + (long)(b * 8 + s8) * PART_STRIDE + i];
        ct[i] = s;
    }
    if (tid < 128) {
        float s = 0.f;
        #pragma unroll
        for (int s8 = 0; s8 < 8; ++s8)
            s += ws[WS_P2 + (long)(b * 8 + s8) * PART_STRIDE + 4096 + tid];
        rsum[tid] = s;
    }
    __syncthreads();
    u32* atb = (u32*)ws + WS_ATB + b * 4096;
    const int o  = tid & 63;
    const int ug = tid >> 6;
    for (int i = 0; i < 16; ++i) {
        const int up = ug * 16 + i;
        const int hc0 = 2 * up, hc1 = 2 * up + 1;
        const int hh = hc0 >> 5;
        const int c0 = hc0 & 31, c1 = hc1 & 31;
        float s0 = 0.f, s1 = 0.f;
        #pragma unroll
        for (int d = 0; d < 32; ++d) {
            const float w = wo[o * 129 + hh * 32 + d];
            s0 = fmaf(w, ct[hh * 1024 + c0 * 32 + d], s0);
            s1 = fmaf(w, ct[hh * 1024 + c1 * 32 + d], s1);
        }
        atb[up * 64 + o] = pk2(s0 / rsum[hc0], s1 / rsum[hc1]);
    }
}

// ---------------- K3: q GEMM (MFMA) + in-reg softmax + A@q (MFMA) --------
// R13: group structure (256-px block, 4 tiles). x staged 1KB-granule as
// bf16-hi (same as k1); W/ATb/bias frags loaded once per 4 tiles; per-tile
// qb round-trip unchanged. LDS 48 KB -> 3 blocks/CU.
__global__ __launch_bounds__(256, 3)
void k3_out(const float* __restrict__ x, const float* __restrict__ wq,
            const float* __restrict__ bout, const float* __restrict__ wsf,
            float* __restrict__ out) {
    __shared__ u32 xbh[256 * 32];      // [px][cpair hi], swizzled, 32 KB
    __shared__ u16 qb[64 * 128];       // [px][hc] bf16, swizzled, 16 KB
    const int blk = blockIdx.x;
    const int p   = threadIdx.x & 63;
    const int og  = __builtin_amdgcn_readfirstlane(threadIdx.x >> 6);
    const int b   = blk / (K1_BLOCKS / 2);
    const int q   = p >> 4;
    const int l15 = p & 15;
    const int yv  = (p & 7) << 2;
    const float* xg = x + (long)b * 64 * NPIX;

    // W frags: q rows og*32..+32, split hi/lo (kept split: W is exact)
    FragU wh[2][2], wl[2][2];
    #pragma unroll
    for (int mi = 0; mi < 2; ++mi)
        #pragma unroll
        for (int ks = 0; ks < 2; ++ks) {
            const int row = og * 32 + mi * 16 + l15;
            const float* wp = wq + row * 64 + ks * 32 + q * 4;
            float4 f0 = *(const float4*)wp;
            float4 f1 = *(const float4*)(wp + 16);
            split2(f0.x, f0.y, wh[mi][ks].u[0], wl[mi][ks].u[0]);
            split2(f0.z, f0.w, wh[mi][ks].u[1], wl[mi][ks].u[1]);
            split2(f1.x, f1.y, wh[mi][ks].u[2], wl[mi][ks].u[2]);
            split2(f1.z, f1.w, wh[mi][ks].u[3], wl[mi][ks].u[3]);
        }

    // ATb frags (per-b matrix, packed bf16 pairs) — once per block
    const u32* atb = (const u32*)wsf + WS_ATB + b * 4096;
    FragU af[4];
    #pragma unroll
    for (int ks = 0; ks < 4; ++ks) {
        const int up0 = ks * 16 + 2 * q;
        const int o   = og * 16 + l15;
        af[ks].u[0] = atb[(up0)     * 64 + o];
        af[ks].u[1] = atb[(up0 + 1) * 64 + o];
        af[ks].u[2] = atb[(up0 + 8) * 64 + o];
        af[ks].u[3] = atb[(up0 + 9) * 64 + o];
    }
    const float4 bias = *(const float4*)&bout[og * 16 + q * 4];

    // stage group's x: 1KB-granule float4 loads, bf16-hi pack (as k1)
    const long i0g = (long)(blk * K1_TPB - b * NTILES) * 64;
    #pragma unroll
    for (int ch = 0; ch < 2; ++ch) {
        f32x4 xl4[8];
        const float* xr = xg + (long)(og * 16 + ch * 8) * NPIX + i0g + 4 * p;
        #pragma unroll
        for (int i = 0; i < 8; ++i) xl4[i] = *(const f32x4*)(xr + (long)i * NPIX);
        #pragma unroll
        for (int j = 0; j < 4; ++j) {
            const int px = 4 * p + j;
            const int yy = (px & 7) << 2;
            u32 h[4];
            #pragma unroll
            for (int w = 0; w < 4; ++w) h[w] = pk2(xl4[2 * w][j], xl4[2 * w + 1][j]);
            const int sA = (og * 8 + ch * 4) ^ yy;
            *(uint4*)&xbh[px * 32 + sA] = make_uint4(h[0], h[1], h[2], h[3]);
        }
    }
    __syncthreads();

    #pragma unroll 1
    for (int tt = 0; tt < K1_TPB; ++tt) {
        const long i0 = i0g + tt * 64;

        // phase 1 + softmax, per px-block ni
        #pragma unroll
        for (int ni = 0; ni < 4; ++ni) {
            const int rb = (tt * 64 + ni * 16 + l15) * 32;
            FragU bh[2];
            #pragma unroll
            for (int ks = 0; ks < 2; ++ks) {
                const int c0 = (ks * 16 + 2 * q) ^ yv;
                const int c1 = (ks * 16 + 2 * q + 8) ^ yv;
                uint2 t0 = *(const uint2*)&xbh[rb + c0];
                uint2 t1 = *(const uint2*)&xbh[rb + c1];
                bh[ks].u[0] = t0.x; bh[ks].u[1] = t0.y;
                bh[ks].u[2] = t1.x; bh[ks].u[3] = t1.y;
            }
            f32x4 a0 = (f32x4)0.f, a1 = (f32x4)0.f;
            #pragma unroll
            for (int ks = 0; ks < 2; ++ks) {
                a0 = MFMA(wh[0][ks].v, bh[ks].v, a0);
                a0 = MFMA(wl[0][ks].v, bh[ks].v, a0);
                a1 = MFMA(wh[1][ks].v, bh[ks].v, a1);
                a1 = MFMA(wl[1][ks].v, bh[ks].v, a1);
            }
            // softmax over head og's 32 rows for this lane's px column
            float mx = a0[0];
            #pragma unroll
            for (int j = 1; j < 4; ++j) mx = fmaxf(mx, a0[j]);
            #pragma unroll
            for (int j = 0; j < 4; ++j) mx = fmaxf(mx, a1[j]);
            mx = fmaxf(mx, __shfl_xor(mx, 16));
            mx = fmaxf(mx, __shfl_xor(mx, 32));
            float e0[4], e1[4], sm = 0.f;
            #pragma unroll
            for (int j = 0; j < 4; ++j) { e0[j] = __expf(a0[j] - mx); sm += e0[j]; }
            #pragma unroll
            for (int j = 0; j < 4; ++j) { e1[j] = __expf(a1[j] - mx); sm += e1[j]; }
            sm += __shfl_xor(sm, 16);
            sm += __shfl_xor(sm, 32);
            const float inv = 1.0f / sm;
            const int px = ni * 16 + l15;
            const int Xq = (px & 7) << 3;          // u16-unit swizzle
            u32* qbw = (u32*)qb;
            const int b0 = (px * 128 + ((og * 32 + q * 4) ^ Xq)) >> 1;
            const int b1 = (px * 128 + ((og * 32 + 16 + q * 4) ^ Xq)) >> 1;
            *(uint2*)&qbw[b0] = make_uint2(pk2(e0[0] * inv, e0[1] * inv),
                                           pk2(e0[2] * inv, e0[3] * inv));
            *(uint2*)&qbw[b1] = make_uint2(pk2(e1[0] * inv, e1[1] * inv),
                                           pk2(e1[2] * inv, e1[3] * inv));
        }
        __syncthreads();               // qb ready

        // phase 3: out = A^T qsm + bias
        const u32* qb32 = (const u32*)qb;
        #pragma unroll
        for (int ni = 0; ni < 4; ++ni) {
            const int px = ni * 16 + l15;
            const int rb = px * 64;
            f32x4 a3 = (f32x4)0.f;
            #pragma unroll
            for (int ks = 0; ks < 4; ++ks) {
                const int c0 = (ks * 16 + 2 * q) ^ yv;
                const int c1 = (ks * 16 + 2 * q + 8) ^ yv;
                uint2 t0 = *(const uint2*)&qb32[rb + c0];
                uint2 t1 = *(const uint2*)&qb32[rb + c1];
                FragU bq;
                bq.u[0] = t0.x; bq.u[1] = t0.y; bq.u[2] = t1.x; bq.u[3] = t1.y;
                a3 = MFMA(af[ks].v, bq.v, a3);
            }
            #pragma unroll
            for (int j = 0; j < 4; ++j)
                out[((long)b * 64 + og * 16 + q * 4 + j) * NPIX + i0 + px] = a3[j] + bias[j];
        }
        __syncthreads();               // qb consumed before next tile's writes
    }
}

extern "C" void kernel_launch(void* const* d_in, const int* in_sizes, int n_in,
                              void* d_out, int out_size, void* d_ws, size_t ws_size,
                              hipStream_t stream) {
    (void)in_sizes; (void)n_in; (void)out_size;
    const float* x     = (const float*)d_in[0];
    const float* w_qkv = (const float*)d_in[1];
    const float* w_out = (const float*)d_in[2];
    const float* b_out = (const float*)d_in[3];
    float* out = (float*)d_out;
    float* ws  = (float*)d_ws;

    const size_t need_part = ((size_t)WS_PART + (size_t)K1_BLOCKS * PART_STRIDE) * 4;
    const int usePart = (ws_size >= need_part) ? 1 : 0;
    int R = 8;
    const size_t need_r8 = ((size_t)WS_PART + (size_t)2 * 8 * PART_STRIDE) * 4;
    if (!usePart && ws_size < need_r8) R = 1;
    const int PB = usePart ? K1_BLOCKS : 2 * R;
    float* part = ws + WS_PART;

    if (!usePart)
        hipMemsetAsync(part, 0, (size_t)PB * PART_STRIDE * 4, stream);
    hipLaunchKernelGGL(k1_ctx, dim3(K1_BLOCKS), dim3(256), 0, stream,
                       x, w_qkv, part, usePart, R);
    hipLaunchKernelGGL(k1b_reduce, dim3(528), dim3(128), 0, stream, ws, PB);
    hipLaunchKernelGGL(k2_prepA, dim3(2), dim3(256), 0, stream, w_out, ws);
    hipLaunchKernelGGL(k3_out, dim3(K1_BLOCKS), dim3(256), 0, stream,
                       x, w_qkv, b_out, ws, out);
}